// Round 4
// baseline (620.755 us; speedup 1.0000x reference)
//
#include <hip/hip_runtime.h>
#include <cstdint>
#include <cstddef>

typedef __bf16 bf16;
typedef __bf16 bf16x4 __attribute__((ext_vector_type(4)));
typedef __bf16 bf16x8 __attribute__((ext_vector_type(8)));
typedef float f32x4 __attribute__((ext_vector_type(4)));

#define MFMA16(a, b, c) __builtin_amdgcn_mfma_f32_16x16x32_bf16((a), (b), (c), 0, 0, 0)

__device__ __forceinline__ float bf2f(bf16 v) { return (float)v; }

__device__ __forceinline__ void pack4(float a0, float a1, float a2, float a3, bf16* dst) {
    bf16x4 v; v[0] = (bf16)a0; v[1] = (bf16)a1; v[2] = (bf16)a2; v[3] = (bf16)a3;
    *(bf16x4*)dst = v;
}

// ---- workspace layout (bytes) ----
#define OFF_SCALES 65536
#define OFF_FLAG   65552
#define OFF_QKVB   65600
#define OFF_PROJB  67136
#define OFF_N1W    67648
#define OFF_N1B    68160
#define OFF_FC1B   68672
#define OFF_FC2B   70720
#define OFF_N2W    71232
#define OFF_N2B    71744
#define OFF_QKVW   73728
#define OFF_PROJW  172032
#define OFF_FC1W   204800
#define OFF_FC2W   335872

// ---- dtype-adaptive global load helper for the big input tensor only ----
template<int DT>
__device__ __forceinline__ void g_ld4(const void* base, size_t idx, float* o) {
    if constexpr (DT == 0) {
        uint2 d = *(const uint2*)((const bf16*)base + idx);
        const bf16* p = (const bf16*)&d;
        o[0] = bf2f(p[0]); o[1] = bf2f(p[1]); o[2] = bf2f(p[2]); o[3] = bf2f(p[3]);
    } else {
        float4 d = *(const float4*)((const float*)base + idx);
        o[0] = d.x; o[1] = d.y; o[2] = d.z; o[3] = d.w;
    }
}

// ---------------- kernel 0: init = dtype detect + CPB table (block 0) + weight convert (blocks 1..96) ----------------
__global__ void k_init(const void* __restrict__ cpb_w1, const void* __restrict__ cpb_b1,
                       const void* __restrict__ cpb_w2, const void* __restrict__ logit_scale,
                       const void* __restrict__ qkv_w, const void* __restrict__ proj_w,
                       const void* __restrict__ fc1w, const void* __restrict__ fc2w,
                       const void* __restrict__ q_bias, const void* __restrict__ v_bias,
                       const void* __restrict__ proj_b, const void* __restrict__ n1w, const void* __restrict__ n1b,
                       const void* __restrict__ fc1b, const void* __restrict__ fc2b,
                       const void* __restrict__ n2w, const void* __restrict__ n2b,
                       char* __restrict__ ws)
{
    const int t = threadIdx.x;
    __shared__ int s_cnt;
    if (t == 0) s_cnt = 0;
    __syncthreads();
    {   // per-block dtype detection: fp32-viewed-as-u16 has ~40% wild exponents
        const unsigned short* u = (const unsigned short*)qkv_w;
        int c = 0;
        for (int i = t; i < 1024; i += 256) {
            const int e = (u[i] >> 7) & 0xFF;
            if (e >= 0x90 || (e != 0 && e <= 0x60)) ++c;
        }
        atomicAdd(&s_cnt, c);
    }
    __syncthreads();
    const int isf = (s_cnt > 64) ? 1 : 0;

    if (blockIdx.x == 0) {
        float* biasAll = (float*)ws;
        float* scales  = (float*)(ws + OFF_SCALES);
        int*   flag    = (int*)(ws + OFF_FLAG);
        if (t == 0) *flag = isf;
        __shared__ float w1s[1024];
        __shared__ float b1s[512];
        __shared__ float w2s[2048];
        __shared__ float tabv[225][4];
        if (isf) {
            const float* w1 = (const float*)cpb_w1;
            const float* b1 = (const float*)cpb_b1;
            const float* w2 = (const float*)cpb_w2;
            for (int i = t; i < 1024; i += 256) w1s[i] = w1[i];
            for (int i = t; i < 512;  i += 256) b1s[i] = b1[i];
            for (int i = t; i < 2048; i += 256) w2s[i] = w2[i];
            if (t < 4) scales[t] = expf(fminf(((const float*)logit_scale)[t], 4.6051701859880914f));
        } else {
            const bf16* w1 = (const bf16*)cpb_w1;
            const bf16* b1 = (const bf16*)cpb_b1;
            const bf16* w2 = (const bf16*)cpb_w2;
            for (int i = t; i < 1024; i += 256) w1s[i] = bf2f(w1[i]);
            for (int i = t; i < 512;  i += 256) b1s[i] = bf2f(b1[i]);
            for (int i = t; i < 2048; i += 256) w2s[i] = bf2f(w2[i]);
            if (t < 4) scales[t] = expf(fminf(bf2f(((const bf16*)logit_scale)[t]), 4.6051701859880914f));
        }
        __syncthreads();
        if (t < 225) {
            const int i = t / 15, j = t % 15;
            auto relf = [](int tt) -> float {
                float tf = (float)tt * (8.0f / 7.0f);
                float a = log2f(fabsf(tf) + 1.0f) * (1.0f / 3.0f);
                return tt < 0 ? -a : a;
            };
            const float x0 = relf(i - 7), x1 = relf(j - 7);
            float a0 = 0.f, a1 = 0.f, a2 = 0.f, a3 = 0.f;
            for (int jj = 0; jj < 512; ++jj) {
                float hv = w1s[jj*2] * x0 + w1s[jj*2+1] * x1 + b1s[jj];
                hv = fmaxf(hv, 0.0f);
                a0 += w2s[jj]        * hv;
                a1 += w2s[512 + jj]  * hv;
                a2 += w2s[1024 + jj] * hv;
                a3 += w2s[1536 + jj] * hv;
            }
            tabv[t][0] = a0; tabv[t][1] = a1; tabv[t][2] = a2; tabv[t][3] = a3;
        }
        __syncthreads();
        for (int idx = t; idx < 4*64*64; idx += 256) {
            const int h = idx >> 12, rem = idx & 4095, i = rem >> 6, j = rem & 63;
            const int di = (i >> 3) - (j >> 3) + 7;
            const int dj = (i & 7) - (j & 7) + 7;
            const float bv = tabv[di*15 + dj][h];
            biasAll[idx] = 16.0f / (1.0f + expf(-bv));
        }
    } else {
        const int g  = (blockIdx.x - 1) * 256 + t;
        const int gs = 96 * 256;
        bf16* qw = (bf16*)(ws + OFF_QKVW);
        bf16* pw = (bf16*)(ws + OFF_PROJW);
        bf16* f1 = (bf16*)(ws + OFF_FC1W);
        bf16* f2 = (bf16*)(ws + OFF_FC2W);
        if (isf) {
            const float* a = (const float*)qkv_w;  for (int i = g; i < 49152; i += gs) qw[i] = (bf16)a[i];
            const float* b = (const float*)proj_w; for (int i = g; i < 16384; i += gs) pw[i] = (bf16)b[i];
            const float* c = (const float*)fc1w;   for (int i = g; i < 65536; i += gs) f1[i] = (bf16)c[i];
            const float* d = (const float*)fc2w;   for (int i = g; i < 65536; i += gs) f2[i] = (bf16)d[i];
        } else {
            const bf16* a = (const bf16*)qkv_w;  for (int i = g; i < 49152; i += gs) qw[i] = a[i];
            const bf16* b = (const bf16*)proj_w; for (int i = g; i < 16384; i += gs) pw[i] = b[i];
            const bf16* c = (const bf16*)fc1w;   for (int i = g; i < 65536; i += gs) f1[i] = c[i];
            const bf16* d = (const bf16*)fc2w;   for (int i = g; i < 65536; i += gs) f2[i] = d[i];
        }
        auto ldf = [&](const void* p, int i) -> float {
            return isf ? ((const float*)p)[i] : bf2f(((const bf16*)p)[i]);
        };
        float* qb  = (float*)(ws + OFF_QKVB);
        float* pb  = (float*)(ws + OFF_PROJB);
        float* w1  = (float*)(ws + OFF_N1W);
        float* b1  = (float*)(ws + OFF_N1B);
        float* f1b = (float*)(ws + OFF_FC1B);
        float* f2b = (float*)(ws + OFF_FC2B);
        float* w2  = (float*)(ws + OFF_N2W);
        float* b2  = (float*)(ws + OFF_N2B);
        for (int i = g; i < 384; i += gs)
            qb[i] = (i < 128) ? ldf(q_bias, i) : ((i < 256) ? 0.0f : ldf(v_bias, i - 256));
        for (int i = g; i < 512; i += gs) f1b[i] = ldf(fc1b, i);
        for (int i = g; i < 128; i += gs) {
            pb[i]  = ldf(proj_b, i); w1[i] = ldf(n1w, i); b1[i] = ldf(n1b, i);
            f2b[i] = ldf(fc2b, i);   w2[i] = ldf(n2w, i); b2[i] = ldf(n2b, i);
        }
    }
}

// ---------------- kernel 1: FULLY FUSED layer, wave=head, XOR-swizzled LDS, 3 blocks/CU ----------------
// LDS layout (52480 B total):
//   XK  @0      : q|k swz [64 tok][512 B]  (32768) ; reuse: PsT [4][64 row][128 B] swz ; x1s [64][136] bf16
//   R3  @32768  : x-tile [64][136] bf16 (17408) ; reuse: vs swz [128 ch][128 B] ; Os/hs/x2s [64][136]
//   psum @50176 : 256 f32 (alias invks) ; pvar @51200 : 256 f32 ; rid @52224 : 64 int
__global__ __launch_bounds__(256, 3) void k_fused(
    const void* __restrict__ x,
    const bf16* __restrict__ qkvw, const float* __restrict__ qkvb,
    const bf16* __restrict__ projw, const float* __restrict__ projb,
    const float* __restrict__ n1wf, const float* __restrict__ n1bf,
    const bf16* __restrict__ fc1w, const float* __restrict__ fc1bf,
    const bf16* __restrict__ fc2w, const float* __restrict__ fc2bf,
    const float* __restrict__ n2wf, const float* __restrict__ n2bf,
    const float* __restrict__ biasAll, const float* __restrict__ scales,
    const int* __restrict__ flag, void* __restrict__ out)
{
    const int isf = *flag;

    __shared__ __align__(16) char smem[52480];
    char* XK   = smem;
    bf16* x1s  = (bf16*)smem;
    char* R3   = smem + 32768;
    bf16* Xs   = (bf16*)R3;
    bf16* Os   = (bf16*)R3;
    bf16* hs   = (bf16*)R3;
    float* psum  = (float*)(smem + 50176);
    float* invks = psum;                    // disjoint lifetime
    float* pvar  = (float*)(smem + 51200);
    int*   rid   = (int*)(smem + 52224);

    const int tid  = threadIdx.x;
    const int wv   = tid >> 6;
    const int lane = tid & 63;
    const int l15  = lane & 15;
    const int quad = lane >> 4;

    // XCD-aware bijective swizzle
    const int bid0 = blockIdx.x;
    const int bid  = ((bid0 & 7) << 9) | (bid0 >> 3);
    const int b   = bid >> 8;
    const int wh  = (bid >> 4) & 15;
    const int ww  = bid & 15;

    // ---- stage 0: gather shifted window into x-tile (R3); region ids ----
    {
        const int c  = tid & 127;
        const int rb = tid >> 7;
        const int w0 = ww*8 + 4;
        const int w1 = (ww*8 + 8) & 127;
#pragma unroll
        for (int k = 0; k < 4; ++k) {
            const int r    = k*2 + rb;
            const int srch = (wh*8 + r + 4) & 127;
            const size_t rowbase = (((size_t)(b*128 + c))*128 + srch)*128;
            float va[4], vb[4];
            if (isf) { g_ld4<1>(x, rowbase + w0, va); g_ld4<1>(x, rowbase + w1, vb); }
            else     { g_ld4<0>(x, rowbase + w0, va); g_ld4<0>(x, rowbase + w1, vb); }
#pragma unroll
            for (int j = 0; j < 4; ++j) {
                Xs[(r*8 + j)*136 + c]     = (bf16)va[j];
                Xs[(r*8 + 4 + j)*136 + c] = (bf16)vb[j];
            }
        }
        if (tid < 64) {
            const int rr = tid >> 3, cc = tid & 7;
            const int hs_ = wh*8 + rr, wsc = ww*8 + cc;
            const int rh = (hs_ < 120) ? 0 : ((hs_ < 124) ? 1 : 2);
            const int rw = (wsc < 120) ? 0 : ((wsc < 124) ? 1 : 2);
            rid[tid] = rh*3 + rw;
        }
    }
    __syncthreads();

    // ---- stage 1: wave=head computes its own q,k (swapped) and v (normal); norms folded in ----
    float iq[4];   // inv q-norm for token mt*16+l15 (all lanes valid after quad-reduce)
    {
        f32x4 acc[6][4];
#pragma unroll
        for (int t = 0; t < 6; ++t)
#pragma unroll
            for (int mt = 0; mt < 4; ++mt) acc[t][mt] = (f32x4){0.f, 0.f, 0.f, 0.f};
#pragma unroll
        for (int ks = 0; ks < 4; ++ks) {
            bf16x8 a[4];
#pragma unroll
            for (int mt = 0; mt < 4; ++mt)
                a[mt] = *(const bf16x8*)&Xs[(mt*16 + l15)*136 + ks*32 + quad*8];
#pragma unroll
            for (int t = 0; t < 6; ++t) {
                const int wrow = (t >> 1)*128 + wv*32 + (t & 1)*16 + l15;
                bf16x8 bw = *(const bf16x8*)&qkvw[(size_t)wrow*128 + ks*32 + quad*8];
                if (t < 4) {   // q,k: swapped -> lane holds (ch=quad*4+r, token=l15)
#pragma unroll
                    for (int mt = 0; mt < 4; ++mt)
                        acc[t][mt] = MFMA16(bw, a[mt], acc[t][mt]);
                } else {       // v: normal -> lane holds (token=quad*4+r, ch=l15)
#pragma unroll
                    for (int mt = 0; mt < 4; ++mt)
                        acc[t][mt] = MFMA16(a[mt], bw, acc[t][mt]);
                }
            }
        }
        __syncthreads();   // all x-tile reads done; R3 becomes vs

        float sq[4] = {0.f,0.f,0.f,0.f};
        float sk[4] = {0.f,0.f,0.f,0.f};
#pragma unroll
        for (int t = 0; t < 4; ++t) {     // q,k -> XK swizzled
            const int colb = (t >> 1)*128 + wv*32 + (t & 1)*16 + quad*4;
            const float4 b4 = *(const float4*)&qkvb[colb];
#pragma unroll
            for (int mt = 0; mt < 4; ++mt) {
                const int row = mt*16 + l15;
                const float v0 = acc[t][mt][0] + b4.x;
                const float v1 = acc[t][mt][1] + b4.y;
                const float v2 = acc[t][mt][2] + b4.z;
                const float v3 = acc[t][mt][3] + b4.w;
                const float ss = v0*v0 + v1*v1 + v2*v2 + v3*v3;
                if (t < 2) sq[mt] += ss; else sk[mt] += ss;
                pack4(v0, v1, v2, v3,
                      (bf16*)(XK + row*512 + ((colb*2) ^ ((row & 7) << 4))));
            }
        }
#pragma unroll
        for (int t = 4; t < 6; ++t) {     // v -> R3 swizzled [ch][tok]
            const int vrow = wv*32 + (t & 1)*16 + l15;
            const float bb = qkvb[256 + vrow];
            char* vbase = R3 + vrow*128;
            const int rx = (vrow & 7) << 4;
#pragma unroll
            for (int mt = 0; mt < 4; ++mt) {
                const int tokb = mt*16 + quad*4;
                pack4(acc[t][mt][0] + bb, acc[t][mt][1] + bb,
                      acc[t][mt][2] + bb, acc[t][mt][3] + bb,
                      (bf16*)(vbase + ((tokb*2) ^ rx)));
            }
        }
#pragma unroll
        for (int mt = 0; mt < 4; ++mt) {
            float s2 = sq[mt];
            s2 += __shfl_xor(s2, 16); s2 += __shfl_xor(s2, 32);
            iq[mt] = 1.0f / fmaxf(sqrtf(s2), 1e-12f);
            float k2 = sk[mt];
            k2 += __shfl_xor(k2, 16); k2 += __shfl_xor(k2, 32);
            if (quad == 0) invks[wv*64 + mt*16 + l15] = 1.0f / fmaxf(sqrtf(k2), 1e-12f);
        }
    }
    // no barrier: stage 3 reads only this wave's q/k/invks

    // ---- stage 3: S^T = K x Q^T; scale+bias+mask; softmax; P^T -> PsT (swz, over q|k) ----
    {
        const float scale = scales[wv];
        f32x4 s[4][4];
#pragma unroll
        for (int jt = 0; jt < 4; ++jt)
#pragma unroll
            for (int it = 0; it < 4; ++it) s[jt][it] = (f32x4){0.f, 0.f, 0.f, 0.f};
        bf16x8 aq[4];
#pragma unroll
        for (int it = 0; it < 4; ++it) {
            const int row = it*16 + l15;
            aq[it] = *(const bf16x8*)(XK + row*512 + (((wv*32 + quad*8)*2) ^ ((row & 7) << 4)));
        }
#pragma unroll
        for (int jt = 0; jt < 4; ++jt) {
            const int row = jt*16 + l15;
            bf16x8 bk = *(const bf16x8*)(XK + row*512 + (((128 + wv*32 + quad*8)*2) ^ ((row & 7) << 4)));
#pragma unroll
            for (int it = 0; it < 4; ++it)
                s[jt][it] = MFMA16(bk, aq[it], s[jt][it]);
        }
        __syncthreads();   // ALL waves' q/k reads done before PsT overlays XK

        const float* bg = biasAll + wv*4096;
        const bool bnd = (wh == 15) || (ww == 15);
        float iqs[4]; int ri[4];
#pragma unroll
        for (int it = 0; it < 4; ++it) {
            iqs[it] = iq[it] * scale;
            ri[it]  = rid[it*16 + l15];
        }
        float4 ikj[4]; int4 rj4[4];
#pragma unroll
        for (int jt = 0; jt < 4; ++jt) {
            ikj[jt] = *(const float4*)&invks[wv*64 + jt*16 + quad*4];
            rj4[jt] = *(const int4*)&rid[jt*16 + quad*4];
        }
#pragma unroll
        for (int it = 0; it < 4; ++it) {
            const int i = it*16 + l15;
#pragma unroll
            for (int jt = 0; jt < 4; ++jt) {
                const float4 bb = *(const float4*)&bg[i*64 + jt*16 + quad*4];
#pragma unroll
                for (int r = 0; r < 4; ++r) {
                    float v = s[jt][it][r] * (iqs[it] * ((const float*)&ikj[jt])[r]) + ((const float*)&bb)[r];
                    if (bnd && (ri[it] != ((const int*)&rj4[jt])[r])) v -= 100.0f;
                    s[jt][it][r] = v;
                }
            }
            float m = s[0][it][0];
#pragma unroll
            for (int jt = 0; jt < 4; ++jt)
#pragma unroll
                for (int r = 0; r < 4; ++r) m = fmaxf(m, s[jt][it][r]);
            m = fmaxf(m, __shfl_xor(m, 16));
            m = fmaxf(m, __shfl_xor(m, 32));
            float sm = 0.f;
#pragma unroll
            for (int jt = 0; jt < 4; ++jt)
#pragma unroll
                for (int r = 0; r < 4; ++r) {
                    const float e = __expf(s[jt][it][r] - m);
                    s[jt][it][r] = e;
                    sm += e;
                }
            sm += __shfl_xor(sm, 16);
            sm += __shfl_xor(sm, 32);
            const float inv = 1.0f / sm;
#pragma unroll
            for (int jt = 0; jt < 4; ++jt)
                pack4(s[jt][it][0]*inv, s[jt][it][1]*inv, s[jt][it][2]*inv, s[jt][it][3]*inv,
                      (bf16*)(XK + wv*8192 + i*128 + ((jt*32 + quad*8) ^ ((i & 7) << 4))));
        }
    }
    // no barrier: stage 4 reads only this wave's PsT block and vs rows

    // ---- stage 4: O^T = V^T x P^T -> Os (plain, over vs after barrier) ----
    {
        f32x4 o[2][4];
#pragma unroll
        for (int dt = 0; dt < 2; ++dt)
#pragma unroll
            for (int it = 0; it < 4; ++it) o[dt][it] = (f32x4){0.f, 0.f, 0.f, 0.f};
#pragma unroll
        for (int ks = 0; ks < 2; ++ks) {
            bf16x8 bp[4];
#pragma unroll
            for (int it = 0; it < 4; ++it) {
                const int row = it*16 + l15;
                bp[it] = *(const bf16x8*)(XK + wv*8192 + row*128 + ((ks*64 + quad*16) ^ ((row & 7) << 4)));
            }
#pragma unroll
            for (int dt = 0; dt < 2; ++dt) {
                const int vrow = wv*32 + dt*16 + l15;
                bf16x8 av = *(const bf16x8*)(R3 + vrow*128 + ((ks*64 + quad*16) ^ ((vrow & 7) << 4)));
#pragma unroll
                for (int it = 0; it < 4; ++it)
                    o[dt][it] = MFMA16(av, bp[it], o[dt][it]);
            }
        }
        __syncthreads();   // all vs/PsT reads done before Os overlays R3
#pragma unroll
        for (int dt = 0; dt < 2; ++dt)
#pragma unroll
            for (int it = 0; it < 4; ++it)
                pack4(o[dt][it][0], o[dt][it][1], o[dt][it][2], o[dt][it][3],
                      &Os[(it*16 + l15)*136 + wv*32 + dt*16 + quad*4]);
    }
    __syncthreads();

    // ---- stage 5: X1^T = projW x O^T + LN1 + residual(re-gathered) -> x1s (over PsT/q|k) ----
    {
        // residual re-gather from global x (L2-hot), re-rounded through bf16
        float res[2][4][4];
#pragma unroll
        for (int tt = 0; tt < 4; ++tt) {
            const int tok = tt*16 + l15;
            const int hh  = (wh*8 + (tok >> 3) + 4) & 127;
            const int wwp = (ww*8 + (tok & 7) + 4) & 127;
            const size_t tb = (size_t)b*2097152 + (size_t)hh*128 + wwp;
#pragma unroll
            for (int ct = 0; ct < 2; ++ct)
#pragma unroll
                for (int r = 0; r < 4; ++r) {
                    const int c = wv*32 + ct*16 + quad*4 + r;
                    float xv;
                    if (isf) xv = ((const float*)x)[tb + (size_t)c*16384];
                    else     xv = bf2f(((const bf16*)x)[tb + (size_t)c*16384]);
                    res[ct][tt][r] = bf2f((bf16)xv);
                }
        }
        f32x4 pa[2][4];
#pragma unroll
        for (int ct = 0; ct < 2; ++ct)
#pragma unroll
            for (int tt = 0; tt < 4; ++tt) pa[ct][tt] = (f32x4){0.f, 0.f, 0.f, 0.f};
#pragma unroll
        for (int ks = 0; ks < 4; ++ks) {
            bf16x8 bo[4];
#pragma unroll
            for (int tt = 0; tt < 4; ++tt)
                bo[tt] = *(const bf16x8*)&Os[(tt*16 + l15)*136 + ks*32 + quad*8];
#pragma unroll
            for (int ct = 0; ct < 2; ++ct) {
                bf16x8 aw = *(const bf16x8*)&projw[(size_t)(wv*32 + ct*16 + l15)*128 + ks*32 + quad*8];
#pragma unroll
                for (int tt = 0; tt < 4; ++tt)
                    pa[ct][tt] = MFMA16(aw, bo[tt], pa[ct][tt]);
            }
        }
        float4 pb4[2], wn4[2], bn4[2];
#pragma unroll
        for (int ct = 0; ct < 2; ++ct) {
            const int ob = wv*32 + ct*16 + quad*4;
            pb4[ct] = *(const float4*)&projb[ob];
            wn4[ct] = *(const float4*)&n1wf[ob];
            bn4[ct] = *(const float4*)&n1bf[ob];
        }
#pragma unroll
        for (int tt = 0; tt < 4; ++tt) {
            float sv = 0.f;
#pragma unroll
            for (int ct = 0; ct < 2; ++ct)
#pragma unroll
                for (int r = 0; r < 4; ++r) {
                    pa[ct][tt][r] += ((const float*)&pb4[ct])[r];
                    sv += pa[ct][tt][r];
                }
            sv += __shfl_xor(sv, 16);
            sv += __shfl_xor(sv, 32);
            if (quad == 0) psum[wv*64 + tt*16 + l15] = sv;
        }
        __syncthreads();
        float mu[4];
#pragma unroll
        for (int tt = 0; tt < 4; ++tt) {
            const int tok = tt*16 + l15;
            mu[tt] = (psum[tok] + psum[64+tok] + psum[128+tok] + psum[192+tok]) * (1.0f/128.0f);
            float sv = 0.f;
#pragma unroll
            for (int ct = 0; ct < 2; ++ct)
#pragma unroll
                for (int r = 0; r < 4; ++r) {
                    const float d = pa[ct][tt][r] - mu[tt];
                    sv += d*d;
                }
            sv += __shfl_xor(sv, 16);
            sv += __shfl_xor(sv, 32);
            if (quad == 0) pvar[wv*64 + tok] = sv;
        }
        __syncthreads();
#pragma unroll
        for (int tt = 0; tt < 4; ++tt) {
            const int tok = tt*16 + l15;
            const float var = (pvar[tok] + pvar[64+tok] + pvar[128+tok] + pvar[192+tok]) * (1.0f/128.0f);
            const float rstd = rsqrtf(var + 1e-5f);
#pragma unroll
            for (int ct = 0; ct < 2; ++ct) {
                const int ob = wv*32 + ct*16 + quad*4;
                float xv[4];
#pragma unroll
                for (int r = 0; r < 4; ++r)
                    xv[r] = res[ct][tt][r] + (pa[ct][tt][r] - mu[tt]) * rstd * ((const float*)&wn4[ct])[r]
                            + ((const float*)&bn4[ct])[r];
                pack4(xv[0], xv[1], xv[2], xv[3], &x1s[tok*136 + ob]);
            }
        }
    }
    __syncthreads();

    // ---- stage 6: MLP fc1+silu+fc2, hidden chunked 4x128 (hs over R3) ----
    f32x4 ya[2][4];
#pragma unroll
    for (int ct = 0; ct < 2; ++ct)
#pragma unroll
        for (int tt = 0; tt < 4; ++tt) ya[ct][tt] = (f32x4){0.f, 0.f, 0.f, 0.f};

#pragma unroll
    for (int ch = 0; ch < 4; ++ch) {
        if (ch) __syncthreads();
        f32x4 ha[2][4];
#pragma unroll
        for (int ht = 0; ht < 2; ++ht)
#pragma unroll
            for (int tt = 0; tt < 4; ++tt) ha[ht][tt] = (f32x4){0.f, 0.f, 0.f, 0.f};
#pragma unroll
        for (int ks = 0; ks < 4; ++ks) {
            bf16x8 bx[4];
#pragma unroll
            for (int tt = 0; tt < 4; ++tt)
                bx[tt] = *(const bf16x8*)&x1s[(tt*16 + l15)*136 + ks*32 + quad*8];
#pragma unroll
            for (int ht = 0; ht < 2; ++ht) {
                bf16x8 aw = *(const bf16x8*)&fc1w[(size_t)(ch*128 + wv*32 + ht*16 + l15)*128 + ks*32 + quad*8];
#pragma unroll
                for (int tt = 0; tt < 4; ++tt)
                    ha[ht][tt] = MFMA16(aw, bx[tt], ha[ht][tt]);
            }
        }
#pragma unroll
        for (int ht = 0; ht < 2; ++ht) {
            const float4 bb4 = *(const float4*)&fc1bf[ch*128 + wv*32 + ht*16 + quad*4];
            const int hb = wv*32 + ht*16 + quad*4;
#pragma unroll
            for (int tt = 0; tt < 4; ++tt) {
                float hv[4];
#pragma unroll
                for (int r = 0; r < 4; ++r) {
                    float v = ha[ht][tt][r] + ((const float*)&bb4)[r];
                    hv[r] = v / (1.0f + __expf(-v));   // silu
                }
                pack4(hv[0], hv[1], hv[2], hv[3], &hs[(tt*16 + l15)*136 + hb]);
            }
        }
        __syncthreads();
#pragma unroll
        for (int ks = 0; ks < 4; ++ks) {
            bf16x8 bh[4];
#pragma unroll
            for (int tt = 0; tt < 4; ++tt)
                bh[tt] = *(const bf16x8*)&hs[(tt*16 + l15)*136 + ks*32 + quad*8];
#pragma unroll
            for (int ct = 0; ct < 2; ++ct) {
                bf16x8 aw = *(const bf16x8*)&fc2w[(size_t)(wv*32 + ct*16 + l15)*512 + ch*128 + ks*32 + quad*8];
#pragma unroll
                for (int tt = 0; tt < 4; ++tt)
                    ya[ct][tt] = MFMA16(aw, bh[tt], ya[ct][tt]);
            }
        }
    }
    __syncthreads();

    // ---- stage 7: bias + LN2 + residual(x1s) -> x2s (over hs) ----
    {
        float4 pb4[2], wn4[2], bn4[2];
#pragma unroll
        for (int ct = 0; ct < 2; ++ct) {
            const int ob = wv*32 + ct*16 + quad*4;
            pb4[ct] = *(const float4*)&fc2bf[ob];
            wn4[ct] = *(const float4*)&n2wf[ob];
            bn4[ct] = *(const float4*)&n2bf[ob];
        }
#pragma unroll
        for (int tt = 0; tt < 4; ++tt) {
            float sv = 0.f;
#pragma unroll
            for (int ct = 0; ct < 2; ++ct)
#pragma unroll
                for (int r = 0; r < 4; ++r) {
                    ya[ct][tt][r] += ((const float*)&pb4[ct])[r];
                    sv += ya[ct][tt][r];
                }
            sv += __shfl_xor(sv, 16);
            sv += __shfl_xor(sv, 32);
            if (quad == 0) psum[wv*64 + tt*16 + l15] = sv;
        }
        __syncthreads();
        float mu[4];
#pragma unroll
        for (int tt = 0; tt < 4; ++tt) {
            const int tok = tt*16 + l15;
            mu[tt] = (psum[tok] + psum[64+tok] + psum[128+tok] + psum[192+tok]) * (1.0f/128.0f);
            float sv = 0.f;
#pragma unroll
            for (int ct = 0; ct < 2; ++ct)
#pragma unroll
                for (int r = 0; r < 4; ++r) {
                    const float d = ya[ct][tt][r] - mu[tt];
                    sv += d*d;
                }
            sv += __shfl_xor(sv, 16);
            sv += __shfl_xor(sv, 32);
            if (quad == 0) pvar[wv*64 + tok] = sv;
        }
        __syncthreads();
        bf16* x2s = hs;
#pragma unroll
        for (int tt = 0; tt < 4; ++tt) {
            const int tok = tt*16 + l15;
            const float var = (pvar[tok] + pvar[64+tok] + pvar[128+tok] + pvar[192+tok]) * (1.0f/128.0f);
            const float rstd = rsqrtf(var + 1e-5f);
#pragma unroll
            for (int ct = 0; ct < 2; ++ct) {
                const int ob = wv*32 + ct*16 + quad*4;
                bf16x4 xr = *(const bf16x4*)&x1s[tok*136 + ob];
                float xv[4];
#pragma unroll
                for (int r = 0; r < 4; ++r)
                    xv[r] = bf2f(xr[r]) + (ya[ct][tt][r] - mu[tt]) * rstd * ((const float*)&wn4[ct])[r]
                            + ((const float*)&bn4[ct])[r];
                pack4(xv[0], xv[1], xv[2], xv[3], &x2s[tok*136 + ob]);
            }
        }
    }
    __syncthreads();

    // ---- stage 8: write x2 to planar (B, C, H, W) at reverse-shifted positions ----
    {
        const bf16* x2s = hs;
        const int wf0 = ww*8 + 4;
        const int wf1 = (ww*8 + 8) & 127;
#pragma unroll
        for (int g = 0; g < 4; ++g) {
            const int idx = g*256 + tid;          // 0..1023 = (rr, c)
            const int c  = idx & 127;
            const int rr = idx >> 7;
            const int hf = (wh*8 + rr + 4) & 127;
            const size_t rowb = ((size_t)(b*128 + c))*16384 + (size_t)hf*128;
            if (!isf) {
                const unsigned short* xu = (const unsigned short*)x2s;
                uint2 u0, u1;
                u0.x = (unsigned)xu[(rr*8+0)*136 + c] | ((unsigned)xu[(rr*8+1)*136 + c] << 16);
                u0.y = (unsigned)xu[(rr*8+2)*136 + c] | ((unsigned)xu[(rr*8+3)*136 + c] << 16);
                u1.x = (unsigned)xu[(rr*8+4)*136 + c] | ((unsigned)xu[(rr*8+5)*136 + c] << 16);
                u1.y = (unsigned)xu[(rr*8+6)*136 + c] | ((unsigned)xu[(rr*8+7)*136 + c] << 16);
                bf16* dstb = (bf16*)out;
                *(uint2*)(dstb + rowb + wf0) = u0;
                *(uint2*)(dstb + rowb + wf1) = u1;
            } else {
                float4 u0, u1;
                u0.x = bf2f(x2s[(rr*8+0)*136 + c]); u0.y = bf2f(x2s[(rr*8+1)*136 + c]);
                u0.z = bf2f(x2s[(rr*8+2)*136 + c]); u0.w = bf2f(x2s[(rr*8+3)*136 + c]);
                u1.x = bf2f(x2s[(rr*8+4)*136 + c]); u1.y = bf2f(x2s[(rr*8+5)*136 + c]);
                u1.z = bf2f(x2s[(rr*8+6)*136 + c]); u1.w = bf2f(x2s[(rr*8+7)*136 + c]);
                float* dstf = (float*)out;
                *(float4*)(dstf + rowb + wf0) = u0;
                *(float4*)(dstf + rowb + wf1) = u1;
            }
        }
    }
}

extern "C" void kernel_launch(void* const* d_in, const int* in_sizes, int n_in,
                              void* d_out, int out_size, void* d_ws, size_t ws_size,
                              hipStream_t stream)
{
    (void)in_sizes; (void)n_in; (void)out_size; (void)ws_size;
    const void* x      = d_in[0];
    const void* n1w    = d_in[1];
    const void* n1b    = d_in[2];
    const void* qkv_w  = d_in[3];
    const void* q_bias = d_in[4];
    const void* v_bias = d_in[5];
    const void* lscale = d_in[6];
    const void* cpb_w1 = d_in[7];
    const void* cpb_b1 = d_in[8];
    const void* cpb_w2 = d_in[9];
    const void* proj_w = d_in[10];
    const void* proj_b = d_in[11];
    const void* n2w    = d_in[12];
    const void* n2b    = d_in[13];
    const void* fc1w   = d_in[14];
    const void* fc1b   = d_in[15];
    const void* fc2w   = d_in[16];
    const void* fc2b   = d_in[17];

    char*  ws      = (char*)d_ws;
    float* biasAll = (float*)ws;
    float* scales  = (float*)(ws + OFF_SCALES);
    int*   flag    = (int*)(ws + OFF_FLAG);

    k_init<<<dim3(97), dim3(256), 0, stream>>>(cpb_w1, cpb_b1, cpb_w2, lscale,
                                               qkv_w, proj_w, fc1w, fc2w,
                                               q_bias, v_bias, proj_b, n1w, n1b,
                                               fc1b, fc2b, n2w, n2b, ws);
    k_fused<<<dim3(4096), dim3(256), 0, stream>>>(x,
        (const bf16*)(ws + OFF_QKVW), (const float*)(ws + OFF_QKVB),
        (const bf16*)(ws + OFF_PROJW), (const float*)(ws + OFF_PROJB),
        (const float*)(ws + OFF_N1W), (const float*)(ws + OFF_N1B),
        (const bf16*)(ws + OFF_FC1W), (const float*)(ws + OFF_FC1B),
        (const bf16*)(ws + OFF_FC2W), (const float*)(ws + OFF_FC2B),
        (const float*)(ws + OFF_N2W), (const float*)(ws + OFF_N2B),
        biasAll, scales, flag, d_out);
}

// Round 5
// 591.028 us; speedup vs baseline: 1.0503x; 1.0503x over previous
//
#include <hip/hip_runtime.h>
#include <cstdint>
#include <cstddef>

typedef __bf16 bf16;
typedef __bf16 bf16x4 __attribute__((ext_vector_type(4)));
typedef __bf16 bf16x8 __attribute__((ext_vector_type(8)));
typedef float f32x4 __attribute__((ext_vector_type(4)));

#define MFMA16(a, b, c) __builtin_amdgcn_mfma_f32_16x16x32_bf16((a), (b), (c), 0, 0, 0)

__device__ __forceinline__ float bf2f(bf16 v) { return (float)v; }

__device__ __forceinline__ void pack4(float a0, float a1, float a2, float a3, bf16* dst) {
    bf16x4 v; v[0] = (bf16)a0; v[1] = (bf16)a1; v[2] = (bf16)a2; v[3] = (bf16)a3;
    *(bf16x4*)dst = v;
}

// ---- workspace layout (bytes) ----
#define OFF_SCALES 65536
#define OFF_FLAG   65552
#define OFF_QKVB   65600
#define OFF_PROJB  67136
#define OFF_N1W    67648
#define OFF_N1B    68160
#define OFF_FC1B   68672
#define OFF_FC2B   70720
#define OFF_N2W    71232
#define OFF_N2B    71744
#define OFF_QKVW   73728
#define OFF_PROJW  172032
#define OFF_FC1W   204800
#define OFF_FC2W   335872

// ---- dtype-adaptive global load helper for the big input tensor only ----
template<int DT>
__device__ __forceinline__ void g_ld4(const void* base, size_t idx, float* o) {
    if constexpr (DT == 0) {
        uint2 d = *(const uint2*)((const bf16*)base + idx);
        const bf16* p = (const bf16*)&d;
        o[0] = bf2f(p[0]); o[1] = bf2f(p[1]); o[2] = bf2f(p[2]); o[3] = bf2f(p[3]);
    } else {
        float4 d = *(const float4*)((const float*)base + idx);
        o[0] = d.x; o[1] = d.y; o[2] = d.z; o[3] = d.w;
    }
}

// ---------------- kernel 0: init = dtype detect + CPB table (block 0) + weight convert (blocks 1..96) ----------------
__global__ void k_init(const void* __restrict__ cpb_w1, const void* __restrict__ cpb_b1,
                       const void* __restrict__ cpb_w2, const void* __restrict__ logit_scale,
                       const void* __restrict__ qkv_w, const void* __restrict__ proj_w,
                       const void* __restrict__ fc1w, const void* __restrict__ fc2w,
                       const void* __restrict__ q_bias, const void* __restrict__ v_bias,
                       const void* __restrict__ proj_b, const void* __restrict__ n1w, const void* __restrict__ n1b,
                       const void* __restrict__ fc1b, const void* __restrict__ fc2b,
                       const void* __restrict__ n2w, const void* __restrict__ n2b,
                       char* __restrict__ ws)
{
    const int t = threadIdx.x;
    __shared__ int s_cnt;
    if (t == 0) s_cnt = 0;
    __syncthreads();
    {   // per-block dtype detection: fp32-viewed-as-u16 has ~40% wild exponents
        const unsigned short* u = (const unsigned short*)qkv_w;
        int c = 0;
        for (int i = t; i < 1024; i += 256) {
            const int e = (u[i] >> 7) & 0xFF;
            if (e >= 0x90 || (e != 0 && e <= 0x60)) ++c;
        }
        atomicAdd(&s_cnt, c);
    }
    __syncthreads();
    const int isf = (s_cnt > 64) ? 1 : 0;

    if (blockIdx.x == 0) {
        float* biasAll = (float*)ws;
        float* scales  = (float*)(ws + OFF_SCALES);
        int*   flag    = (int*)(ws + OFF_FLAG);
        if (t == 0) *flag = isf;
        __shared__ float w1s[1024];
        __shared__ float b1s[512];
        __shared__ float w2s[2048];
        __shared__ float tabv[225][4];
        if (isf) {
            const float* w1 = (const float*)cpb_w1;
            const float* b1 = (const float*)cpb_b1;
            const float* w2 = (const float*)cpb_w2;
            for (int i = t; i < 1024; i += 256) w1s[i] = w1[i];
            for (int i = t; i < 512;  i += 256) b1s[i] = b1[i];
            for (int i = t; i < 2048; i += 256) w2s[i] = w2[i];
            if (t < 4) scales[t] = expf(fminf(((const float*)logit_scale)[t], 4.6051701859880914f));
        } else {
            const bf16* w1 = (const bf16*)cpb_w1;
            const bf16* b1 = (const bf16*)cpb_b1;
            const bf16* w2 = (const bf16*)cpb_w2;
            for (int i = t; i < 1024; i += 256) w1s[i] = bf2f(w1[i]);
            for (int i = t; i < 512;  i += 256) b1s[i] = bf2f(b1[i]);
            for (int i = t; i < 2048; i += 256) w2s[i] = bf2f(w2[i]);
            if (t < 4) scales[t] = expf(fminf(bf2f(((const bf16*)logit_scale)[t]), 4.6051701859880914f));
        }
        __syncthreads();
        if (t < 225) {
            const int i = t / 15, j = t % 15;
            auto relf = [](int tt) -> float {
                float tf = (float)tt * (8.0f / 7.0f);
                float a = log2f(fabsf(tf) + 1.0f) * (1.0f / 3.0f);
                return tt < 0 ? -a : a;
            };
            const float x0 = relf(i - 7), x1 = relf(j - 7);
            float a0 = 0.f, a1 = 0.f, a2 = 0.f, a3 = 0.f;
            for (int jj = 0; jj < 512; ++jj) {
                float hv = w1s[jj*2] * x0 + w1s[jj*2+1] * x1 + b1s[jj];
                hv = fmaxf(hv, 0.0f);
                a0 += w2s[jj]        * hv;
                a1 += w2s[512 + jj]  * hv;
                a2 += w2s[1024 + jj] * hv;
                a3 += w2s[1536 + jj] * hv;
            }
            tabv[t][0] = a0; tabv[t][1] = a1; tabv[t][2] = a2; tabv[t][3] = a3;
        }
        __syncthreads();
        for (int idx = t; idx < 4*64*64; idx += 256) {
            const int h = idx >> 12, rem = idx & 4095, i = rem >> 6, j = rem & 63;
            const int di = (i >> 3) - (j >> 3) + 7;
            const int dj = (i & 7) - (j & 7) + 7;
            const float bv = tabv[di*15 + dj][h];
            biasAll[idx] = 16.0f / (1.0f + expf(-bv));
        }
    } else {
        const int g  = (blockIdx.x - 1) * 256 + t;
        const int gs = 96 * 256;
        bf16* qw = (bf16*)(ws + OFF_QKVW);
        bf16* pw = (bf16*)(ws + OFF_PROJW);
        bf16* f1 = (bf16*)(ws + OFF_FC1W);
        bf16* f2 = (bf16*)(ws + OFF_FC2W);
        if (isf) {
            const float* a = (const float*)qkv_w;  for (int i = g; i < 49152; i += gs) qw[i] = (bf16)a[i];
            const float* b = (const float*)proj_w; for (int i = g; i < 16384; i += gs) pw[i] = (bf16)b[i];
            const float* c = (const float*)fc1w;   for (int i = g; i < 65536; i += gs) f1[i] = (bf16)c[i];
            const float* d = (const float*)fc2w;   for (int i = g; i < 65536; i += gs) f2[i] = (bf16)d[i];
        } else {
            const bf16* a = (const bf16*)qkv_w;  for (int i = g; i < 49152; i += gs) qw[i] = a[i];
            const bf16* b = (const bf16*)proj_w; for (int i = g; i < 16384; i += gs) pw[i] = b[i];
            const bf16* c = (const bf16*)fc1w;   for (int i = g; i < 65536; i += gs) f1[i] = c[i];
            const bf16* d = (const bf16*)fc2w;   for (int i = g; i < 65536; i += gs) f2[i] = d[i];
        }
        auto ldf = [&](const void* p, int i) -> float {
            return isf ? ((const float*)p)[i] : bf2f(((const bf16*)p)[i]);
        };
        float* qb  = (float*)(ws + OFF_QKVB);
        float* pb  = (float*)(ws + OFF_PROJB);
        float* w1  = (float*)(ws + OFF_N1W);
        float* b1  = (float*)(ws + OFF_N1B);
        float* f1b = (float*)(ws + OFF_FC1B);
        float* f2b = (float*)(ws + OFF_FC2B);
        float* w2  = (float*)(ws + OFF_N2W);
        float* b2  = (float*)(ws + OFF_N2B);
        for (int i = g; i < 384; i += gs)
            qb[i] = (i < 128) ? ldf(q_bias, i) : ((i < 256) ? 0.0f : ldf(v_bias, i - 256));
        for (int i = g; i < 512; i += gs) f1b[i] = ldf(fc1b, i);
        for (int i = g; i < 128; i += gs) {
            pb[i]  = ldf(proj_b, i); w1[i] = ldf(n1w, i); b1[i] = ldf(n1b, i);
            f2b[i] = ldf(fc2b, i);   w2[i] = ldf(n2w, i); b2[i] = ldf(n2b, i);
        }
    }
}

// ---------------- kernel 1: FULLY FUSED layer, wave=head end-to-end through attention ----------------
// one block per (batch, window): 4096 blocks, 256 threads; 2 blocks/CU (LDS 75008)
// r3-verified buffer layout; r4-verified wave=head stage-1 with folded q/k norms.
__global__ __launch_bounds__(256, 2) void k_fused(
    const void* __restrict__ x,
    const bf16* __restrict__ qkvw, const float* __restrict__ qkvb,
    const bf16* __restrict__ projw, const float* __restrict__ projb,
    const float* __restrict__ n1wf, const float* __restrict__ n1bf,
    const bf16* __restrict__ fc1w, const float* __restrict__ fc1bf,
    const bf16* __restrict__ fc2w, const float* __restrict__ fc2bf,
    const float* __restrict__ n2wf, const float* __restrict__ n2bf,
    const float* __restrict__ biasAll, const float* __restrict__ scales,
    const int* __restrict__ flag, void* __restrict__ out)
{
    const int isf = *flag;

    __shared__ __align__(16) char smem[75008];
    bf16* Xs    = (bf16*)smem;                   // [64][136] window input / residual
    bf16* qkvs  = (bf16*)(smem + 17408);         // [64][264] q|k ; reuse: PsT[4][64][72] ; x1s[64][136]
    bf16* PsT   = qkvs;
    bf16* x1s   = qkvs;
    bf16* vs    = (bf16*)(smem + 54272);         // [128][72] v^T ; reuse: Os[64][136] ; hs[64][136] ; x2s
    bf16* Os    = vs;
    bf16* hs    = vs;
    float* psum  = (float*)(smem + 72704);       // 256 f32 (LN partial sums)
    float* invks = (float*)(smem + 73728);       // 256 f32 ; reuse: LN partial sq-dev (pvar)
    float* pvar  = invks;
    int*   rid   = (int*)(smem + 74752);         // 64

    const int tid  = threadIdx.x;
    const int wv   = tid >> 6;
    const int lane = tid & 63;
    const int l15  = lane & 15;
    const int quad = lane >> 4;

    // XCD-aware bijective swizzle
    const int bid0 = blockIdx.x;
    const int bid  = ((bid0 & 7) << 9) | (bid0 >> 3);
    const int b   = bid >> 8;
    const int wh  = (bid >> 4) & 15;
    const int ww  = bid & 15;

    // ---- stage 0: gather shifted window into Xs[token][c]; region ids ----
    {
        const int c  = tid & 127;
        const int rb = tid >> 7;
        const int w0 = ww*8 + 4;
        const int w1 = (ww*8 + 8) & 127;
#pragma unroll
        for (int k = 0; k < 4; ++k) {
            const int r    = k*2 + rb;
            const int srch = (wh*8 + r + 4) & 127;
            const size_t rowbase = (((size_t)(b*128 + c))*128 + srch)*128;
            float va[4], vb[4];
            if (isf) { g_ld4<1>(x, rowbase + w0, va); g_ld4<1>(x, rowbase + w1, vb); }
            else     { g_ld4<0>(x, rowbase + w0, va); g_ld4<0>(x, rowbase + w1, vb); }
#pragma unroll
            for (int j = 0; j < 4; ++j) {
                Xs[(r*8 + j)*136 + c]     = (bf16)va[j];
                Xs[(r*8 + 4 + j)*136 + c] = (bf16)vb[j];
            }
        }
        if (tid < 64) {
            const int rr = tid >> 3, cc = tid & 7;
            const int hs_ = wh*8 + rr, wsc = ww*8 + cc;
            const int rh = (hs_ < 120) ? 0 : ((hs_ < 124) ? 1 : 2);
            const int rw = (wsc < 120) ? 0 : ((wsc < 124) ? 1 : 2);
            rid[tid] = rh*3 + rw;
        }
    }
    __syncthreads();

    // ---- stage 1: wave=head computes its own q,k (swapped) and v (normal); norms folded in ----
    float iq[4];   // inv q-norm for token mt*16+l15
    {
        f32x4 acc[6][4];
#pragma unroll
        for (int t = 0; t < 6; ++t)
#pragma unroll
            for (int mt = 0; mt < 4; ++mt) acc[t][mt] = (f32x4){0.f, 0.f, 0.f, 0.f};
#pragma unroll
        for (int ks = 0; ks < 4; ++ks) {
            bf16x8 a[4];
#pragma unroll
            for (int mt = 0; mt < 4; ++mt)
                a[mt] = *(const bf16x8*)&Xs[(mt*16 + l15)*136 + ks*32 + quad*8];
#pragma unroll
            for (int t = 0; t < 6; ++t) {
                const int wrow = (t >> 1)*128 + wv*32 + (t & 1)*16 + l15;
                bf16x8 bw = *(const bf16x8*)&qkvw[(size_t)wrow*128 + ks*32 + quad*8];
                if (t < 4) {   // q,k swapped: lane holds (ch=colb+quad*4+r, token=mt*16+l15)
#pragma unroll
                    for (int mt = 0; mt < 4; ++mt)
                        acc[t][mt] = MFMA16(bw, a[mt], acc[t][mt]);
                } else {       // v normal: lane holds (token=mt*16+quad*4+r, ch=base+l15)
#pragma unroll
                    for (int mt = 0; mt < 4; ++mt)
                        acc[t][mt] = MFMA16(a[mt], bw, acc[t][mt]);
                }
            }
        }
        float sq[4] = {0.f,0.f,0.f,0.f};
        float sk[4] = {0.f,0.f,0.f,0.f};
#pragma unroll
        for (int t = 0; t < 4; ++t) {     // q,k -> qkvs[token][ch] (padded 264)
            const int colb = (t >> 1)*128 + wv*32 + (t & 1)*16 + quad*4;
            const float4 b4 = *(const float4*)&qkvb[colb];
#pragma unroll
            for (int mt = 0; mt < 4; ++mt) {
                const int row = mt*16 + l15;
                const float v0 = acc[t][mt][0] + b4.x;
                const float v1 = acc[t][mt][1] + b4.y;
                const float v2 = acc[t][mt][2] + b4.z;
                const float v3 = acc[t][mt][3] + b4.w;
                const float ss = v0*v0 + v1*v1 + v2*v2 + v3*v3;
                if (t < 2) sq[mt] += ss; else sk[mt] += ss;
                pack4(v0, v1, v2, v3, &qkvs[row*264 + colb]);
            }
        }
#pragma unroll
        for (int t = 4; t < 6; ++t) {     // v -> vs[ch][token] (padded 72)
            const int vrow = wv*32 + (t & 1)*16 + l15;
            const float bb = qkvb[256 + vrow];
#pragma unroll
            for (int mt = 0; mt < 4; ++mt)
                pack4(acc[t][mt][0] + bb, acc[t][mt][1] + bb,
                      acc[t][mt][2] + bb, acc[t][mt][3] + bb,
                      &vs[vrow*72 + mt*16 + quad*4]);
        }
#pragma unroll
        for (int mt = 0; mt < 4; ++mt) {
            float s2 = sq[mt];
            s2 += __shfl_xor(s2, 16); s2 += __shfl_xor(s2, 32);
            iq[mt] = 1.0f / fmaxf(sqrtf(s2), 1e-12f);
            float k2 = sk[mt];
            k2 += __shfl_xor(k2, 16); k2 += __shfl_xor(k2, 32);
            if (quad == 0) invks[wv*64 + mt*16 + l15] = 1.0f / fmaxf(sqrtf(k2), 1e-12f);
        }
    }
    // no barrier: stage 3 reads only this wave's q/k/invks (all produced by this wave)

    // ---- stage 3: S^T = K x Q^T; scale+bias+mask; softmax over j; P^T -> PsT (over qkvs) ----
    {
        const float scale = scales[wv];
        f32x4 s[4][4];   // [jt][it]: j = jt*16+quad*4+r, i = it*16+l15
#pragma unroll
        for (int jt = 0; jt < 4; ++jt)
#pragma unroll
            for (int it = 0; it < 4; ++it) s[jt][it] = (f32x4){0.f, 0.f, 0.f, 0.f};
        bf16x8 aq[4];
#pragma unroll
        for (int it = 0; it < 4; ++it)
            aq[it] = *(const bf16x8*)&qkvs[(it*16 + l15)*264 + wv*32 + quad*8];
#pragma unroll
        for (int jt = 0; jt < 4; ++jt) {
            bf16x8 bk = *(const bf16x8*)&qkvs[(jt*16 + l15)*264 + 128 + wv*32 + quad*8];
#pragma unroll
            for (int it = 0; it < 4; ++it)
                s[jt][it] = MFMA16(bk, aq[it], s[jt][it]);
        }
        __syncthreads();   // ALL waves' q/k reads done before PsT overlays qkvs

        const float* bg = biasAll + wv*4096;
        const bool bnd = (wh == 15) || (ww == 15);
        float iqs[4]; int ri[4];
#pragma unroll
        for (int it = 0; it < 4; ++it) {
            iqs[it] = iq[it] * scale;
            ri[it]  = rid[it*16 + l15];
        }
        float4 ikj[4]; int4 rj4[4];
#pragma unroll
        for (int jt = 0; jt < 4; ++jt) {
            ikj[jt] = *(const float4*)&invks[wv*64 + jt*16 + quad*4];
            rj4[jt] = *(const int4*)&rid[jt*16 + quad*4];
        }
#pragma unroll
        for (int it = 0; it < 4; ++it) {
            const int i = it*16 + l15;
#pragma unroll
            for (int jt = 0; jt < 4; ++jt) {
                const float4 bb = *(const float4*)&bg[i*64 + jt*16 + quad*4];
#pragma unroll
                for (int r = 0; r < 4; ++r) {
                    float v = s[jt][it][r] * (iqs[it] * ((const float*)&ikj[jt])[r]) + ((const float*)&bb)[r];
                    if (bnd && (ri[it] != ((const int*)&rj4[jt])[r])) v -= 100.0f;
                    s[jt][it][r] = v;
                }
            }
            float m = s[0][it][0];
#pragma unroll
            for (int jt = 0; jt < 4; ++jt)
#pragma unroll
                for (int r = 0; r < 4; ++r) m = fmaxf(m, s[jt][it][r]);
            m = fmaxf(m, __shfl_xor(m, 16));
            m = fmaxf(m, __shfl_xor(m, 32));
            float sm = 0.f;
#pragma unroll
            for (int jt = 0; jt < 4; ++jt)
#pragma unroll
                for (int r = 0; r < 4; ++r) {
                    const float e = __expf(s[jt][it][r] - m);
                    s[jt][it][r] = e;
                    sm += e;
                }
            sm += __shfl_xor(sm, 16);
            sm += __shfl_xor(sm, 32);
            const float inv = 1.0f / sm;
#pragma unroll
            for (int jt = 0; jt < 4; ++jt)
                pack4(s[jt][it][0]*inv, s[jt][it][1]*inv, s[jt][it][2]*inv, s[jt][it][3]*inv,
                      &PsT[wv*4608 + i*72 + jt*16 + quad*4]);
        }
    }
    // no barrier: stage 4 reads only this wave's PsT block and this wave's (own-head) vs rows

    // ---- stage 4: O^T = V^T x P^T -> packed row-major Os[token][ch] (overlays vs after barrier) ----
    {
        f32x4 o[2][4];   // [dt][it]: ch = wv*32+dt*16+quad*4+r, token = it*16+l15
#pragma unroll
        for (int dt = 0; dt < 2; ++dt)
#pragma unroll
            for (int it = 0; it < 4; ++it) o[dt][it] = (f32x4){0.f, 0.f, 0.f, 0.f};
#pragma unroll
        for (int ks = 0; ks < 2; ++ks) {
            bf16x8 bp[4];
#pragma unroll
            for (int it = 0; it < 4; ++it)
                bp[it] = *(const bf16x8*)&PsT[wv*4608 + (it*16 + l15)*72 + ks*32 + quad*8];
#pragma unroll
            for (int dt = 0; dt < 2; ++dt) {
                bf16x8 av = *(const bf16x8*)&vs[(wv*32 + dt*16 + l15)*72 + ks*32 + quad*8];
#pragma unroll
                for (int it = 0; it < 4; ++it)
                    o[dt][it] = MFMA16(av, bp[it], o[dt][it]);
            }
        }
        __syncthreads();   // all waves' vs reads done before Os overlays vs
#pragma unroll
        for (int dt = 0; dt < 2; ++dt)
#pragma unroll
            for (int it = 0; it < 4; ++it)
                pack4(o[dt][it][0], o[dt][it][1], o[dt][it][2], o[dt][it][3],
                      &Os[(it*16 + l15)*136 + wv*32 + dt*16 + quad*4]);
    }
    __syncthreads();

    // ---- stage 5: X1^T = projW x O^T (swapped) + LN1 + residual(Xs) -> packed x1s ----
    {
        f32x4 pa[2][4];  // [ct][tt]: oc = wv*32+ct*16+quad*4+r, token = tt*16+l15
#pragma unroll
        for (int ct = 0; ct < 2; ++ct)
#pragma unroll
            for (int tt = 0; tt < 4; ++tt) pa[ct][tt] = (f32x4){0.f, 0.f, 0.f, 0.f};
#pragma unroll
        for (int ks = 0; ks < 4; ++ks) {
            bf16x8 bo[4];
#pragma unroll
            for (int tt = 0; tt < 4; ++tt)
                bo[tt] = *(const bf16x8*)&Os[(tt*16 + l15)*136 + ks*32 + quad*8];
#pragma unroll
            for (int ct = 0; ct < 2; ++ct) {
                bf16x8 aw = *(const bf16x8*)&projw[(size_t)(wv*32 + ct*16 + l15)*128 + ks*32 + quad*8];
#pragma unroll
                for (int tt = 0; tt < 4; ++tt)
                    pa[ct][tt] = MFMA16(aw, bo[tt], pa[ct][tt]);
            }
        }
        float4 pb4[2], wn4[2], bn4[2];
#pragma unroll
        for (int ct = 0; ct < 2; ++ct) {
            const int ob = wv*32 + ct*16 + quad*4;
            pb4[ct] = *(const float4*)&projb[ob];
            wn4[ct] = *(const float4*)&n1wf[ob];
            bn4[ct] = *(const float4*)&n1bf[ob];
        }
#pragma unroll
        for (int tt = 0; tt < 4; ++tt) {
            float sv = 0.f;
#pragma unroll
            for (int ct = 0; ct < 2; ++ct)
#pragma unroll
                for (int r = 0; r < 4; ++r) {
                    pa[ct][tt][r] += ((const float*)&pb4[ct])[r];
                    sv += pa[ct][tt][r];
                }
            sv += __shfl_xor(sv, 16);
            sv += __shfl_xor(sv, 32);
            if (quad == 0) psum[wv*64 + tt*16 + l15] = sv;
        }
        __syncthreads();
        float mu[4];
#pragma unroll
        for (int tt = 0; tt < 4; ++tt) {
            const int tok = tt*16 + l15;
            mu[tt] = (psum[tok] + psum[64+tok] + psum[128+tok] + psum[192+tok]) * (1.0f/128.0f);
            float sv = 0.f;
#pragma unroll
            for (int ct = 0; ct < 2; ++ct)
#pragma unroll
                for (int r = 0; r < 4; ++r) {
                    const float d = pa[ct][tt][r] - mu[tt];
                    sv += d*d;
                }
            sv += __shfl_xor(sv, 16);
            sv += __shfl_xor(sv, 32);
            if (quad == 0) pvar[wv*64 + tok] = sv;
        }
        __syncthreads();
#pragma unroll
        for (int tt = 0; tt < 4; ++tt) {
            const int tok = tt*16 + l15;
            const float var = (pvar[tok] + pvar[64+tok] + pvar[128+tok] + pvar[192+tok]) * (1.0f/128.0f);
            const float rstd = rsqrtf(var + 1e-5f);
#pragma unroll
            for (int ct = 0; ct < 2; ++ct) {
                const int ob = wv*32 + ct*16 + quad*4;
                bf16x4 xr = *(const bf16x4*)&Xs[tok*136 + ob];
                float xv[4];
#pragma unroll
                for (int r = 0; r < 4; ++r)
                    xv[r] = bf2f(xr[r]) + (pa[ct][tt][r] - mu[tt]) * rstd * ((const float*)&wn4[ct])[r]
                            + ((const float*)&bn4[ct])[r];
                pack4(xv[0], xv[1], xv[2], xv[3], &x1s[tok*136 + ob]);
            }
        }
    }
    __syncthreads();

    // ---- stage 6: MLP fc1+silu+fc2 (swapped, packed), hidden chunked 4x128 (hs over vs/Os) ----
    f32x4 ya[2][4];
#pragma unroll
    for (int ct = 0; ct < 2; ++ct)
#pragma unroll
        for (int tt = 0; tt < 4; ++tt) ya[ct][tt] = (f32x4){0.f, 0.f, 0.f, 0.f};

#pragma unroll
    for (int ch = 0; ch < 4; ++ch) {
        if (ch) __syncthreads();   // previous chunk's fc2 reads of hs must finish
        f32x4 ha[2][4];
#pragma unroll
        for (int ht = 0; ht < 2; ++ht)
#pragma unroll
            for (int tt = 0; tt < 4; ++tt) ha[ht][tt] = (f32x4){0.f, 0.f, 0.f, 0.f};
#pragma unroll
        for (int ks = 0; ks < 4; ++ks) {
            bf16x8 bx[4];
#pragma unroll
            for (int tt = 0; tt < 4; ++tt)
                bx[tt] = *(const bf16x8*)&x1s[(tt*16 + l15)*136 + ks*32 + quad*8];
#pragma unroll
            for (int ht = 0; ht < 2; ++ht) {
                bf16x8 aw = *(const bf16x8*)&fc1w[(size_t)(ch*128 + wv*32 + ht*16 + l15)*128 + ks*32 + quad*8];
#pragma unroll
                for (int tt = 0; tt < 4; ++tt)
                    ha[ht][tt] = MFMA16(aw, bx[tt], ha[ht][tt]);
            }
        }
#pragma unroll
        for (int ht = 0; ht < 2; ++ht) {
            const float4 bb4 = *(const float4*)&fc1bf[ch*128 + wv*32 + ht*16 + quad*4];
            const int hb = wv*32 + ht*16 + quad*4;
#pragma unroll
            for (int tt = 0; tt < 4; ++tt) {
                float hv[4];
#pragma unroll
                for (int r = 0; r < 4; ++r) {
                    float v = ha[ht][tt][r] + ((const float*)&bb4)[r];
                    hv[r] = v / (1.0f + __expf(-v));   // silu
                }
                pack4(hv[0], hv[1], hv[2], hv[3], &hs[(tt*16 + l15)*136 + hb]);
            }
        }
        __syncthreads();
#pragma unroll
        for (int ks = 0; ks < 4; ++ks) {
            bf16x8 bh[4];
#pragma unroll
            for (int tt = 0; tt < 4; ++tt)
                bh[tt] = *(const bf16x8*)&hs[(tt*16 + l15)*136 + ks*32 + quad*8];
#pragma unroll
            for (int ct = 0; ct < 2; ++ct) {
                bf16x8 aw = *(const bf16x8*)&fc2w[(size_t)(wv*32 + ct*16 + l15)*512 + ch*128 + ks*32 + quad*8];
#pragma unroll
                for (int tt = 0; tt < 4; ++tt)
                    ya[ct][tt] = MFMA16(aw, bh[tt], ya[ct][tt]);
            }
        }
    }
    __syncthreads();   // all fc2 reads of hs done before reuse as x2 staging

    // ---- stage 7: bias + LN2 + residual(x1s) -> x2s (overlays hs) ----
    {
        float4 pb4[2], wn4[2], bn4[2];
#pragma unroll
        for (int ct = 0; ct < 2; ++ct) {
            const int ob = wv*32 + ct*16 + quad*4;
            pb4[ct] = *(const float4*)&fc2bf[ob];
            wn4[ct] = *(const float4*)&n2wf[ob];
            bn4[ct] = *(const float4*)&n2bf[ob];
        }
#pragma unroll
        for (int tt = 0; tt < 4; ++tt) {
            float sv = 0.f;
#pragma unroll
            for (int ct = 0; ct < 2; ++ct)
#pragma unroll
                for (int r = 0; r < 4; ++r) {
                    ya[ct][tt][r] += ((const float*)&pb4[ct])[r];
                    sv += ya[ct][tt][r];
                }
            sv += __shfl_xor(sv, 16);
            sv += __shfl_xor(sv, 32);
            if (quad == 0) psum[wv*64 + tt*16 + l15] = sv;
        }
        __syncthreads();
        float mu[4];
#pragma unroll
        for (int tt = 0; tt < 4; ++tt) {
            const int tok = tt*16 + l15;
            mu[tt] = (psum[tok] + psum[64+tok] + psum[128+tok] + psum[192+tok]) * (1.0f/128.0f);
            float sv = 0.f;
#pragma unroll
            for (int ct = 0; ct < 2; ++ct)
#pragma unroll
                for (int r = 0; r < 4; ++r) {
                    const float d = ya[ct][tt][r] - mu[tt];
                    sv += d*d;
                }
            sv += __shfl_xor(sv, 16);
            sv += __shfl_xor(sv, 32);
            if (quad == 0) pvar[wv*64 + tok] = sv;
        }
        __syncthreads();
        bf16* x2s = hs;
#pragma unroll
        for (int tt = 0; tt < 4; ++tt) {
            const int tok = tt*16 + l15;
            const float var = (pvar[tok] + pvar[64+tok] + pvar[128+tok] + pvar[192+tok]) * (1.0f/128.0f);
            const float rstd = rsqrtf(var + 1e-5f);
#pragma unroll
            for (int ct = 0; ct < 2; ++ct) {
                const int ob = wv*32 + ct*16 + quad*4;
                bf16x4 xr = *(const bf16x4*)&x1s[tok*136 + ob];
                float xv[4];
#pragma unroll
                for (int r = 0; r < 4; ++r)
                    xv[r] = bf2f(xr[r]) + (ya[ct][tt][r] - mu[tt]) * rstd * ((const float*)&wn4[ct])[r]
                            + ((const float*)&bn4[ct])[r];
                pack4(xv[0], xv[1], xv[2], xv[3], &x2s[tok*136 + ob]);
            }
        }
    }
    __syncthreads();

    // ---- stage 8: write x2 to planar (B, C, H, W) at reverse-shifted positions ----
    {
        const bf16* x2s = hs;
        const int wf0 = ww*8 + 4;
        const int wf1 = (ww*8 + 8) & 127;
#pragma unroll
        for (int g = 0; g < 4; ++g) {
            const int idx = g*256 + tid;          // 0..1023 = (rr, c)
            const int c  = idx & 127;
            const int rr = idx >> 7;
            const int hf = (wh*8 + rr + 4) & 127;
            const size_t rowb = ((size_t)(b*128 + c))*16384 + (size_t)hf*128;
            if (!isf) {
                const unsigned short* xu = (const unsigned short*)x2s;
                uint2 u0, u1;
                u0.x = (unsigned)xu[(rr*8+0)*136 + c] | ((unsigned)xu[(rr*8+1)*136 + c] << 16);
                u0.y = (unsigned)xu[(rr*8+2)*136 + c] | ((unsigned)xu[(rr*8+3)*136 + c] << 16);
                u1.x = (unsigned)xu[(rr*8+4)*136 + c] | ((unsigned)xu[(rr*8+5)*136 + c] << 16);
                u1.y = (unsigned)xu[(rr*8+6)*136 + c] | ((unsigned)xu[(rr*8+7)*136 + c] << 16);
                bf16* dstb = (bf16*)out;
                *(uint2*)(dstb + rowb + wf0) = u0;
                *(uint2*)(dstb + rowb + wf1) = u1;
            } else {
                float4 u0, u1;
                u0.x = bf2f(x2s[(rr*8+0)*136 + c]); u0.y = bf2f(x2s[(rr*8+1)*136 + c]);
                u0.z = bf2f(x2s[(rr*8+2)*136 + c]); u0.w = bf2f(x2s[(rr*8+3)*136 + c]);
                u1.x = bf2f(x2s[(rr*8+4)*136 + c]); u1.y = bf2f(x2s[(rr*8+5)*136 + c]);
                u1.z = bf2f(x2s[(rr*8+6)*136 + c]); u1.w = bf2f(x2s[(rr*8+7)*136 + c]);
                float* dstf = (float*)out;
                *(float4*)(dstf + rowb + wf0) = u0;
                *(float4*)(dstf + rowb + wf1) = u1;
            }
        }
    }
}

extern "C" void kernel_launch(void* const* d_in, const int* in_sizes, int n_in,
                              void* d_out, int out_size, void* d_ws, size_t ws_size,
                              hipStream_t stream)
{
    (void)in_sizes; (void)n_in; (void)out_size; (void)ws_size;
    const void* x      = d_in[0];
    const void* n1w    = d_in[1];
    const void* n1b    = d_in[2];
    const void* qkv_w  = d_in[3];
    const void* q_bias = d_in[4];
    const void* v_bias = d_in[5];
    const void* lscale = d_in[6];
    const void* cpb_w1 = d_in[7];
    const void* cpb_b1 = d_in[8];
    const void* cpb_w2 = d_in[9];
    const void* proj_w = d_in[10];
    const void* proj_b = d_in[11];
    const void* n2w    = d_in[12];
    const void* n2b    = d_in[13];
    const void* fc1w   = d_in[14];
    const void* fc1b   = d_in[15];
    const void* fc2w   = d_in[16];
    const void* fc2b   = d_in[17];

    char*  ws      = (char*)d_ws;
    float* biasAll = (float*)ws;
    float* scales  = (float*)(ws + OFF_SCALES);
    int*   flag    = (int*)(ws + OFF_FLAG);

    k_init<<<dim3(97), dim3(256), 0, stream>>>(cpb_w1, cpb_b1, cpb_w2, lscale,
                                               qkv_w, proj_w, fc1w, fc2w,
                                               q_bias, v_bias, proj_b, n1w, n1b,
                                               fc1b, fc2b, n2w, n2b, ws);
    k_fused<<<dim3(4096), dim3(256), 0, stream>>>(x,
        (const bf16*)(ws + OFF_QKVW), (const float*)(ws + OFF_QKVB),
        (const bf16*)(ws + OFF_PROJW), (const float*)(ws + OFF_PROJB),
        (const float*)(ws + OFF_N1W), (const float*)(ws + OFF_N1B),
        (const bf16*)(ws + OFF_FC1W), (const float*)(ws + OFF_FC1B),
        (const bf16*)(ws + OFF_FC2W), (const float*)(ws + OFF_FC2B),
        (const float*)(ws + OFF_N2W), (const float*)(ws + OFF_N2B),
        biasAll, scales, flag, d_out);
}

// Round 7
// 578.623 us; speedup vs baseline: 1.0728x; 1.0214x over previous
//
#include <hip/hip_runtime.h>
#include <cstdint>
#include <cstddef>

typedef __bf16 bf16;
typedef __bf16 bf16x4 __attribute__((ext_vector_type(4)));
typedef __bf16 bf16x8 __attribute__((ext_vector_type(8)));
typedef float f32x4 __attribute__((ext_vector_type(4)));

#define MFMA16(a, b, c) __builtin_amdgcn_mfma_f32_16x16x32_bf16((a), (b), (c), 0, 0, 0)

// XOR swizzle: spread row-strided accesses across banks; preserves 16B alignment
#define SWZ(row, byteoff) ((byteoff) ^ (((row) & 7) << 4))

__device__ __forceinline__ float bf2f(bf16 v) { return (float)v; }

__device__ __forceinline__ void pack4(float a0, float a1, float a2, float a3, bf16* dst) {
    bf16x4 v; v[0] = (bf16)a0; v[1] = (bf16)a1; v[2] = (bf16)a2; v[3] = (bf16)a3;
    *(bf16x4*)dst = v;
}

// ---- workspace layout (bytes) ----
#define OFF_SCALES 65536
#define OFF_FLAG   65552
#define OFF_QKVB   65600
#define OFF_PROJB  67136
#define OFF_N1W    67648
#define OFF_N1B    68160
#define OFF_FC1B   68672
#define OFF_FC2B   70720
#define OFF_N2W    71232
#define OFF_N2B    71744
#define OFF_QKVW   73728
#define OFF_PROJW  172032
#define OFF_FC1W   204800
#define OFF_FC2W   335872

// ---- dtype-adaptive global load helper for the big input tensor only ----
template<int DT>
__device__ __forceinline__ void g_ld4(const void* base, size_t idx, float* o) {
    if constexpr (DT == 0) {
        uint2 d = *(const uint2*)((const bf16*)base + idx);
        const bf16* p = (const bf16*)&d;
        o[0] = bf2f(p[0]); o[1] = bf2f(p[1]); o[2] = bf2f(p[2]); o[3] = bf2f(p[3]);
    } else {
        float4 d = *(const float4*)((const float*)base + idx);
        o[0] = d.x; o[1] = d.y; o[2] = d.z; o[3] = d.w;
    }
}

// ---------------- kernel 0: init = dtype detect + CPB table (block 0) + weight convert (blocks 1..96) ----------------
__global__ void k_init(const void* __restrict__ cpb_w1, const void* __restrict__ cpb_b1,
                       const void* __restrict__ cpb_w2, const void* __restrict__ logit_scale,
                       const void* __restrict__ qkv_w, const void* __restrict__ proj_w,
                       const void* __restrict__ fc1w, const void* __restrict__ fc2w,
                       const void* __restrict__ q_bias, const void* __restrict__ v_bias,
                       const void* __restrict__ proj_b, const void* __restrict__ n1w, const void* __restrict__ n1b,
                       const void* __restrict__ fc1b, const void* __restrict__ fc2b,
                       const void* __restrict__ n2w, const void* __restrict__ n2b,
                       char* __restrict__ ws)
{
    const int t = threadIdx.x;
    __shared__ int s_cnt;
    if (t == 0) s_cnt = 0;
    __syncthreads();
    {   // per-block dtype detection: fp32-viewed-as-u16 has ~40% wild exponents
        const unsigned short* u = (const unsigned short*)qkv_w;
        int c = 0;
        for (int i = t; i < 1024; i += 256) {
            const int e = (u[i] >> 7) & 0xFF;
            if (e >= 0x90 || (e != 0 && e <= 0x60)) ++c;
        }
        atomicAdd(&s_cnt, c);
    }
    __syncthreads();
    const int isf = (s_cnt > 64) ? 1 : 0;

    if (blockIdx.x == 0) {
        float* biasAll = (float*)ws;
        float* scales  = (float*)(ws + OFF_SCALES);
        int*   flag    = (int*)(ws + OFF_FLAG);
        if (t == 0) *flag = isf;
        __shared__ float w1s[1024];
        __shared__ float b1s[512];
        __shared__ float w2s[2048];
        __shared__ float tabv[225][4];
        if (isf) {
            const float* w1 = (const float*)cpb_w1;
            const float* b1 = (const float*)cpb_b1;
            const float* w2 = (const float*)cpb_w2;
            for (int i = t; i < 1024; i += 256) w1s[i] = w1[i];
            for (int i = t; i < 512;  i += 256) b1s[i] = b1[i];
            for (int i = t; i < 2048; i += 256) w2s[i] = w2[i];
            if (t < 4) scales[t] = expf(fminf(((const float*)logit_scale)[t], 4.6051701859880914f));
        } else {
            const bf16* w1 = (const bf16*)cpb_w1;
            const bf16* b1 = (const bf16*)cpb_b1;
            const bf16* w2 = (const bf16*)cpb_w2;
            for (int i = t; i < 1024; i += 256) w1s[i] = bf2f(w1[i]);
            for (int i = t; i < 512;  i += 256) b1s[i] = bf2f(b1[i]);
            for (int i = t; i < 2048; i += 256) w2s[i] = bf2f(w2[i]);
            if (t < 4) scales[t] = expf(fminf(bf2f(((const bf16*)logit_scale)[t]), 4.6051701859880914f));
        }
        __syncthreads();
        if (t < 225) {
            const int i = t / 15, j = t % 15;
            auto relf = [](int tt) -> float {
                float tf = (float)tt * (8.0f / 7.0f);
                float a = log2f(fabsf(tf) + 1.0f) * (1.0f / 3.0f);
                return tt < 0 ? -a : a;
            };
            const float x0 = relf(i - 7), x1 = relf(j - 7);
            float a0 = 0.f, a1 = 0.f, a2 = 0.f, a3 = 0.f;
            for (int jj = 0; jj < 512; ++jj) {
                float hv = w1s[jj*2] * x0 + w1s[jj*2+1] * x1 + b1s[jj];
                hv = fmaxf(hv, 0.0f);
                a0 += w2s[jj]        * hv;
                a1 += w2s[512 + jj]  * hv;
                a2 += w2s[1024 + jj] * hv;
                a3 += w2s[1536 + jj] * hv;
            }
            tabv[t][0] = a0; tabv[t][1] = a1; tabv[t][2] = a2; tabv[t][3] = a3;
        }
        __syncthreads();
        for (int idx = t; idx < 4*64*64; idx += 256) {
            const int h = idx >> 12, rem = idx & 4095, i = rem >> 6, j = rem & 63;
            const int di = (i >> 3) - (j >> 3) + 7;
            const int dj = (i & 7) - (j & 7) + 7;
            const float bv = tabv[di*15 + dj][h];
            biasAll[idx] = 16.0f / (1.0f + expf(-bv));
        }
    } else {
        const int g  = (blockIdx.x - 1) * 256 + t;
        const int gs = 96 * 256;
        bf16* qw = (bf16*)(ws + OFF_QKVW);
        bf16* pw = (bf16*)(ws + OFF_PROJW);
        bf16* f1 = (bf16*)(ws + OFF_FC1W);
        bf16* f2 = (bf16*)(ws + OFF_FC2W);
        if (isf) {
            const float* a = (const float*)qkv_w;  for (int i = g; i < 49152; i += gs) qw[i] = (bf16)a[i];
            const float* b = (const float*)proj_w; for (int i = g; i < 16384; i += gs) pw[i] = (bf16)b[i];
            const float* c = (const float*)fc1w;   for (int i = g; i < 65536; i += gs) f1[i] = (bf16)c[i];
            const float* d = (const float*)fc2w;   for (int i = g; i < 65536; i += gs) f2[i] = (bf16)d[i];
        } else {
            const bf16* a = (const bf16*)qkv_w;  for (int i = g; i < 49152; i += gs) qw[i] = a[i];
            const bf16* b = (const bf16*)proj_w; for (int i = g; i < 16384; i += gs) pw[i] = b[i];
            const bf16* c = (const bf16*)fc1w;   for (int i = g; i < 65536; i += gs) f1[i] = c[i];
            const bf16* d = (const bf16*)fc2w;   for (int i = g; i < 65536; i += gs) f2[i] = d[i];
        }
        auto ldf = [&](const void* p, int i) -> float {
            return isf ? ((const float*)p)[i] : bf2f(((const bf16*)p)[i]);
        };
        float* qb  = (float*)(ws + OFF_QKVB);
        float* pb  = (float*)(ws + OFF_PROJB);
        float* w1  = (float*)(ws + OFF_N1W);
        float* b1  = (float*)(ws + OFF_N1B);
        float* f1b = (float*)(ws + OFF_FC1B);
        float* f2b = (float*)(ws + OFF_FC2B);
        float* w2  = (float*)(ws + OFF_N2W);
        float* b2  = (float*)(ws + OFF_N2B);
        for (int i = g; i < 384; i += gs)
            qb[i] = (i < 128) ? ldf(q_bias, i) : ((i < 256) ? 0.0f : ldf(v_bias, i - 256));
        for (int i = g; i < 512; i += gs) f1b[i] = ldf(fc1b, i);
        for (int i = g; i < 128; i += gs) {
            pb[i]  = ldf(proj_b, i); w1[i] = ldf(n1w, i); b1[i] = ldf(n1b, i);
            f2b[i] = ldf(fc2b, i);   w2[i] = ldf(n2w, i); b2[i] = ldf(n2b, i);
        }
    }
}

// ---------------- kernel 1: FULLY FUSED layer; exact-size XOR-swizzled LDS; 3 blocks/CU ----------------
// LDS map (51456 B):
//   A @0      (32768): x-tile [64][256B swz] -> q|k [64][512B swz] -> PsT [4][64][128B swz] -> x1s [64][256B swz]
//   B @32768  (16384): v^T [128][128B swz] -> Os/hs/x2s [64][256B swz]
//   psum @49152 (1024) ; pvar/invks @50176 (1024) ; rid @51200 (256)
// residual lives in REGISTERS. stage 1 split: v-pass (writes virgin Bv, no barrier) then q/k-pass.
__global__ __launch_bounds__(256, 3) void k_fused(
    const void* __restrict__ x,
    const bf16* __restrict__ qkvw, const float* __restrict__ qkvb,
    const bf16* __restrict__ projw, const float* __restrict__ projb,
    const float* __restrict__ n1wf, const float* __restrict__ n1bf,
    const bf16* __restrict__ fc1w, const float* __restrict__ fc1bf,
    const bf16* __restrict__ fc2w, const float* __restrict__ fc2bf,
    const float* __restrict__ n2wf, const float* __restrict__ n2bf,
    const float* __restrict__ biasAll, const float* __restrict__ scales,
    const int* __restrict__ flag, void* __restrict__ out)
{
    const int isf = *flag;

    __shared__ __align__(16) char smem[51456];
    char* A  = smem;
    char* Bv = smem + 32768;
    float* psum  = (float*)(smem + 49152);
    float* invks = (float*)(smem + 50176);
    float* pvar  = invks;                 // disjoint lifetime (invks dead after stage 3)
    int*   rid   = (int*)(smem + 51200);

    const int tid  = threadIdx.x;
    const int wv   = tid >> 6;
    const int lane = tid & 63;
    const int l15  = lane & 15;
    const int quad = lane >> 4;

    // XCD-aware bijective swizzle
    const int bid0 = blockIdx.x;
    const int bid  = ((bid0 & 7) << 9) | (bid0 >> 3);
    const int b   = bid >> 8;
    const int wh  = (bid >> 4) & 15;
    const int ww  = bid & 15;

    // ---- stage 0: gather shifted window into x-tile A[tok][256B swz]; region ids ----
    {
        const int c  = tid & 127;
        const int rb = tid >> 7;
        const int w0 = ww*8 + 4;
        const int w1 = (ww*8 + 8) & 127;
#pragma unroll
        for (int k = 0; k < 4; ++k) {
            const int r    = k*2 + rb;
            const int srch = (wh*8 + r + 4) & 127;
            const size_t rowbase = (((size_t)(b*128 + c))*128 + srch)*128;
            float va[4], vb[4];
            if (isf) { g_ld4<1>(x, rowbase + w0, va); g_ld4<1>(x, rowbase + w1, vb); }
            else     { g_ld4<0>(x, rowbase + w0, va); g_ld4<0>(x, rowbase + w1, vb); }
#pragma unroll
            for (int j = 0; j < 4; ++j) {
                const int r0 = r*8 + j, r1 = r*8 + 4 + j;
                *(bf16*)(A + r0*256 + SWZ(r0, c*2)) = (bf16)va[j];
                *(bf16*)(A + r1*256 + SWZ(r1, c*2)) = (bf16)vb[j];
            }
        }
        if (tid < 64) {
            const int rr = tid >> 3, cc = tid & 7;
            const int hs_ = wh*8 + rr, wsc = ww*8 + cc;
            const int rh = (hs_ < 120) ? 0 : ((hs_ < 124) ? 1 : 2);
            const int rw = (wsc < 120) ? 0 : ((wsc < 124) ? 1 : 2);
            rid[tid] = rh*3 + rw;
        }
    }
    __syncthreads();

    // ---- stage 1: wave=head. Pass A: v (normal MFMA) -> Bv (virgin, no barrier).
    //      Pass B: q,k (swapped MFMA); residual to regs; barrier; q|k overlays x-tile. ----
    float iq[4];
    bf16x4 resv[2][4];   // residual: [ct][tt] -> token tt*16+l15, ch wv*32+ct*16+quad*4..+3
    {
        // ---- pass A: v tiles ----
        f32x4 accv[2][4];
#pragma unroll
        for (int t = 0; t < 2; ++t)
#pragma unroll
            for (int mt = 0; mt < 4; ++mt) accv[t][mt] = (f32x4){0.f, 0.f, 0.f, 0.f};
#pragma unroll
        for (int ks = 0; ks < 4; ++ks) {
            bf16x8 a[4];
#pragma unroll
            for (int mt = 0; mt < 4; ++mt) {
                const int row = mt*16 + l15;
                a[mt] = *(const bf16x8*)(A + row*256 + SWZ(row, ks*64 + quad*16));
            }
#pragma unroll
            for (int t = 0; t < 2; ++t) {
                const int wrow = 256 + wv*32 + t*16 + l15;
                bf16x8 bw = *(const bf16x8*)&qkvw[(size_t)wrow*128 + ks*32 + quad*8];
#pragma unroll
                for (int mt = 0; mt < 4; ++mt)
                    accv[t][mt] = MFMA16(a[mt], bw, accv[t][mt]);
            }
        }
#pragma unroll
        for (int t = 0; t < 2; ++t) {     // v -> Bv [ch][128B swz] (virgin region, no barrier)
            const int vrow = wv*32 + t*16 + l15;
            const float bb = qkvb[256 + vrow];
#pragma unroll
            for (int mt = 0; mt < 4; ++mt) {
                const int tokb = mt*16 + quad*4;
                pack4(accv[t][mt][0] + bb, accv[t][mt][1] + bb,
                      accv[t][mt][2] + bb, accv[t][mt][3] + bb,
                      (bf16*)(Bv + vrow*128 + SWZ(vrow, tokb*2)));
            }
        }

        // ---- pass B: q,k tiles (swapped) ----
        f32x4 acc[4][4];
#pragma unroll
        for (int t = 0; t < 4; ++t)
#pragma unroll
            for (int mt = 0; mt < 4; ++mt) acc[t][mt] = (f32x4){0.f, 0.f, 0.f, 0.f};
#pragma unroll
        for (int ks = 0; ks < 4; ++ks) {
            bf16x8 a[4];
#pragma unroll
            for (int mt = 0; mt < 4; ++mt) {
                const int row = mt*16 + l15;
                a[mt] = *(const bf16x8*)(A + row*256 + SWZ(row, ks*64 + quad*16));
            }
#pragma unroll
            for (int t = 0; t < 4; ++t) {
                const int wrow = (t >> 1)*128 + wv*32 + (t & 1)*16 + l15;
                bf16x8 bw = *(const bf16x8*)&qkvw[(size_t)wrow*128 + ks*32 + quad*8];
#pragma unroll
                for (int mt = 0; mt < 4; ++mt)
                    acc[t][mt] = MFMA16(bw, a[mt], acc[t][mt]);
            }
        }
        // capture residual (stage-5 layout) before x-tile is overwritten
#pragma unroll
        for (int tt = 0; tt < 4; ++tt) {
            const int tok = tt*16 + l15;
#pragma unroll
            for (int ct = 0; ct < 2; ++ct) {
                const int ob = wv*32 + ct*16 + quad*4;
                resv[ct][tt] = *(const bf16x4*)(A + tok*256 + SWZ(tok, ob*2));
            }
        }
        __syncthreads();   // ALL waves' x-tile reads done; A becomes q|k

        float sq[4] = {0.f,0.f,0.f,0.f};
        float sk[4] = {0.f,0.f,0.f,0.f};
#pragma unroll
        for (int t = 0; t < 4; ++t) {     // q,k -> A [tok][512B swz]
            const int colb = (t >> 1)*128 + wv*32 + (t & 1)*16 + quad*4;
            const float4 b4 = *(const float4*)&qkvb[colb];
#pragma unroll
            for (int mt = 0; mt < 4; ++mt) {
                const int row = mt*16 + l15;
                const float v0 = acc[t][mt][0] + b4.x;
                const float v1 = acc[t][mt][1] + b4.y;
                const float v2 = acc[t][mt][2] + b4.z;
                const float v3 = acc[t][mt][3] + b4.w;
                const float ss = v0*v0 + v1*v1 + v2*v2 + v3*v3;
                if (t < 2) sq[mt] += ss; else sk[mt] += ss;
                pack4(v0, v1, v2, v3, (bf16*)(A + row*512 + SWZ(row, colb*2)));
            }
        }
#pragma unroll
        for (int mt = 0; mt < 4; ++mt) {
            float s2 = sq[mt];
            s2 += __shfl_xor(s2, 16); s2 += __shfl_xor(s2, 32);
            iq[mt] = 1.0f / fmaxf(sqrtf(s2), 1e-12f);
            float k2 = sk[mt];
            k2 += __shfl_xor(k2, 16); k2 += __shfl_xor(k2, 32);
            if (quad == 0) invks[wv*64 + mt*16 + l15] = 1.0f / fmaxf(sqrtf(k2), 1e-12f);
        }
    }
    // no barrier: stage 3 reads only this wave's q/k/invks

    // ---- stage 3: S^T = K x Q^T; scale+bias+mask; softmax; P^T -> PsT (overlays q|k) ----
    {
        const float scale = scales[wv];
        f32x4 s[4][4];
#pragma unroll
        for (int jt = 0; jt < 4; ++jt)
#pragma unroll
            for (int it = 0; it < 4; ++it) s[jt][it] = (f32x4){0.f, 0.f, 0.f, 0.f};
        bf16x8 aq[4];
#pragma unroll
        for (int it = 0; it < 4; ++it) {
            const int row = it*16 + l15;
            aq[it] = *(const bf16x8*)(A + row*512 + SWZ(row, (wv*32 + quad*8)*2));
        }
#pragma unroll
        for (int jt = 0; jt < 4; ++jt) {
            const int row = jt*16 + l15;
            bf16x8 bk = *(const bf16x8*)(A + row*512 + SWZ(row, (128 + wv*32 + quad*8)*2));
#pragma unroll
            for (int it = 0; it < 4; ++it)
                s[jt][it] = MFMA16(bk, aq[it], s[jt][it]);
        }
        __syncthreads();   // ALL waves' q/k reads done before PsT overlays A

        const float* bg = biasAll + wv*4096;
        const bool bnd = (wh == 15) || (ww == 15);
        float iqs[4]; int ri[4];
#pragma unroll
        for (int it = 0; it < 4; ++it) {
            iqs[it] = iq[it] * scale;
            ri[it]  = rid[it*16 + l15];
        }
        float4 ikj[4]; int4 rj4[4];
#pragma unroll
        for (int jt = 0; jt < 4; ++jt) {
            ikj[jt] = *(const float4*)&invks[wv*64 + jt*16 + quad*4];
            rj4[jt] = *(const int4*)&rid[jt*16 + quad*4];
        }
#pragma unroll
        for (int it = 0; it < 4; ++it) {
            const int i = it*16 + l15;
#pragma unroll
            for (int jt = 0; jt < 4; ++jt) {
                const float4 bb = *(const float4*)&bg[i*64 + jt*16 + quad*4];
#pragma unroll
                for (int r = 0; r < 4; ++r) {
                    float v = s[jt][it][r] * (iqs[it] * ((const float*)&ikj[jt])[r]) + ((const float*)&bb)[r];
                    if (bnd && (ri[it] != ((const int*)&rj4[jt])[r])) v -= 100.0f;
                    s[jt][it][r] = v;
                }
            }
            float m = s[0][it][0];
#pragma unroll
            for (int jt = 0; jt < 4; ++jt)
#pragma unroll
                for (int r = 0; r < 4; ++r) m = fmaxf(m, s[jt][it][r]);
            m = fmaxf(m, __shfl_xor(m, 16));
            m = fmaxf(m, __shfl_xor(m, 32));
            float sm = 0.f;
#pragma unroll
            for (int jt = 0; jt < 4; ++jt)
#pragma unroll
                for (int r = 0; r < 4; ++r) {
                    const float e = __expf(s[jt][it][r] - m);
                    s[jt][it][r] = e;
                    sm += e;
                }
            sm += __shfl_xor(sm, 16);
            sm += __shfl_xor(sm, 32);
            const float inv = 1.0f / sm;
#pragma unroll
            for (int jt = 0; jt < 4; ++jt)
                pack4(s[jt][it][0]*inv, s[jt][it][1]*inv, s[jt][it][2]*inv, s[jt][it][3]*inv,
                      (bf16*)(A + wv*8192 + i*128 + SWZ(i, jt*32 + quad*8)));
        }
    }
    // no barrier: stage 4 reads only this wave's PsT block and own-head V rows

    // ---- stage 4: O^T = V^T x P^T -> Os [tok][256B swz] (overlays V after barrier) ----
    {
        f32x4 o[2][4];
#pragma unroll
        for (int dt = 0; dt < 2; ++dt)
#pragma unroll
            for (int it = 0; it < 4; ++it) o[dt][it] = (f32x4){0.f, 0.f, 0.f, 0.f};
#pragma unroll
        for (int ks = 0; ks < 2; ++ks) {
            bf16x8 bp[4];
#pragma unroll
            for (int it = 0; it < 4; ++it) {
                const int row = it*16 + l15;
                bp[it] = *(const bf16x8*)(A + wv*8192 + row*128 + SWZ(row, ks*64 + quad*16));
            }
#pragma unroll
            for (int dt = 0; dt < 2; ++dt) {
                const int vrow = wv*32 + dt*16 + l15;
                bf16x8 av = *(const bf16x8*)(Bv + vrow*128 + SWZ(vrow, ks*64 + quad*16));
#pragma unroll
                for (int it = 0; it < 4; ++it)
                    o[dt][it] = MFMA16(av, bp[it], o[dt][it]);
            }
        }
        __syncthreads();   // all V reads done before Os overlays B
#pragma unroll
        for (int dt = 0; dt < 2; ++dt)
#pragma unroll
            for (int it = 0; it < 4; ++it) {
                const int tok = it*16 + l15;
                pack4(o[dt][it][0], o[dt][it][1], o[dt][it][2], o[dt][it][3],
                      (bf16*)(Bv + tok*256 + SWZ(tok, (wv*32 + dt*16 + quad*4)*2)));
            }
    }
    __syncthreads();

    // ---- stage 5: X1^T = projW x O^T + LN1 + residual(regs) -> x1s (overlays PsT region) ----
    {
        f32x4 pa[2][4];
#pragma unroll
        for (int ct = 0; ct < 2; ++ct)
#pragma unroll
            for (int tt = 0; tt < 4; ++tt) pa[ct][tt] = (f32x4){0.f, 0.f, 0.f, 0.f};
#pragma unroll
        for (int ks = 0; ks < 4; ++ks) {
            bf16x8 bo[4];
#pragma unroll
            for (int tt = 0; tt < 4; ++tt) {
                const int tok = tt*16 + l15;
                bo[tt] = *(const bf16x8*)(Bv + tok*256 + SWZ(tok, ks*64 + quad*16));
            }
#pragma unroll
            for (int ct = 0; ct < 2; ++ct) {
                bf16x8 aw = *(const bf16x8*)&projw[(size_t)(wv*32 + ct*16 + l15)*128 + ks*32 + quad*8];
#pragma unroll
                for (int tt = 0; tt < 4; ++tt)
                    pa[ct][tt] = MFMA16(aw, bo[tt], pa[ct][tt]);
            }
        }
        float4 pb4[2], wn4[2], bn4[2];
#pragma unroll
        for (int ct = 0; ct < 2; ++ct) {
            const int ob = wv*32 + ct*16 + quad*4;
            pb4[ct] = *(const float4*)&projb[ob];
            wn4[ct] = *(const float4*)&n1wf[ob];
            bn4[ct] = *(const float4*)&n1bf[ob];
        }
#pragma unroll
        for (int tt = 0; tt < 4; ++tt) {
            float sv = 0.f;
#pragma unroll
            for (int ct = 0; ct < 2; ++ct)
#pragma unroll
                for (int r = 0; r < 4; ++r) {
                    pa[ct][tt][r] += ((const float*)&pb4[ct])[r];
                    sv += pa[ct][tt][r];
                }
            sv += __shfl_xor(sv, 16);
            sv += __shfl_xor(sv, 32);
            if (quad == 0) psum[wv*64 + tt*16 + l15] = sv;
        }
        __syncthreads();
        float mu[4];
#pragma unroll
        for (int tt = 0; tt < 4; ++tt) {
            const int tok = tt*16 + l15;
            mu[tt] = (psum[tok] + psum[64+tok] + psum[128+tok] + psum[192+tok]) * (1.0f/128.0f);
            float sv = 0.f;
#pragma unroll
            for (int ct = 0; ct < 2; ++ct)
#pragma unroll
                for (int r = 0; r < 4; ++r) {
                    const float d = pa[ct][tt][r] - mu[tt];
                    sv += d*d;
                }
            sv += __shfl_xor(sv, 16);
            sv += __shfl_xor(sv, 32);
            if (quad == 0) pvar[wv*64 + tok] = sv;
        }
        __syncthreads();
#pragma unroll
        for (int tt = 0; tt < 4; ++tt) {
            const int tok = tt*16 + l15;
            const float var = (pvar[tok] + pvar[64+tok] + pvar[128+tok] + pvar[192+tok]) * (1.0f/128.0f);
            const float rstd = rsqrtf(var + 1e-5f);
#pragma unroll
            for (int ct = 0; ct < 2; ++ct) {
                const int ob = wv*32 + ct*16 + quad*4;
                float xv[4];
#pragma unroll
                for (int r = 0; r < 4; ++r)
                    xv[r] = bf2f(resv[ct][tt][r]) + (pa[ct][tt][r] - mu[tt]) * rstd * ((const float*)&wn4[ct])[r]
                            + ((const float*)&bn4[ct])[r];
                pack4(xv[0], xv[1], xv[2], xv[3], (bf16*)(A + tok*256 + SWZ(tok, ob*2)));
            }
        }
    }
    __syncthreads();

    // ---- stage 6: MLP fc1+silu+fc2, hidden chunked 4x128 (hs over B) ----
    f32x4 ya[2][4];
#pragma unroll
    for (int ct = 0; ct < 2; ++ct)
#pragma unroll
        for (int tt = 0; tt < 4; ++tt) ya[ct][tt] = (f32x4){0.f, 0.f, 0.f, 0.f};

#pragma unroll
    for (int ch = 0; ch < 4; ++ch) {
        if (ch) __syncthreads();   // previous chunk's fc2 reads of hs must finish
        f32x4 ha[2][4];
#pragma unroll
        for (int ht = 0; ht < 2; ++ht)
#pragma unroll
            for (int tt = 0; tt < 4; ++tt) ha[ht][tt] = (f32x4){0.f, 0.f, 0.f, 0.f};
#pragma unroll
        for (int ks = 0; ks < 4; ++ks) {
            bf16x8 bx[4];
#pragma unroll
            for (int tt = 0; tt < 4; ++tt) {
                const int tok = tt*16 + l15;
                bx[tt] = *(const bf16x8*)(A + tok*256 + SWZ(tok, ks*64 + quad*16));
            }
#pragma unroll
            for (int ht = 0; ht < 2; ++ht) {
                bf16x8 aw = *(const bf16x8*)&fc1w[(size_t)(ch*128 + wv*32 + ht*16 + l15)*128 + ks*32 + quad*8];
#pragma unroll
                for (int tt = 0; tt < 4; ++tt)
                    ha[ht][tt] = MFMA16(aw, bx[tt], ha[ht][tt]);
            }
        }
#pragma unroll
        for (int ht = 0; ht < 2; ++ht) {
            const float4 bb4 = *(const float4*)&fc1bf[ch*128 + wv*32 + ht*16 + quad*4];
            const int hb = wv*32 + ht*16 + quad*4;
#pragma unroll
            for (int tt = 0; tt < 4; ++tt) {
                const int tok = tt*16 + l15;
                float hv[4];
#pragma unroll
                for (int r = 0; r < 4; ++r) {
                    float v = ha[ht][tt][r] + ((const float*)&bb4)[r];
                    hv[r] = v / (1.0f + __expf(-v));   // silu
                }
                pack4(hv[0], hv[1], hv[2], hv[3], (bf16*)(Bv + tok*256 + SWZ(tok, hb*2)));
            }
        }
        __syncthreads();
#pragma unroll
        for (int ks = 0; ks < 4; ++ks) {
            bf16x8 bh[4];
#pragma unroll
            for (int tt = 0; tt < 4; ++tt) {
                const int tok = tt*16 + l15;
                bh[tt] = *(const bf16x8*)(Bv + tok*256 + SWZ(tok, ks*64 + quad*16));
            }
#pragma unroll
            for (int ct = 0; ct < 2; ++ct) {
                bf16x8 aw = *(const bf16x8*)&fc2w[(size_t)(wv*32 + ct*16 + l15)*512 + ch*128 + ks*32 + quad*8];
#pragma unroll
                for (int tt = 0; tt < 4; ++tt)
                    ya[ct][tt] = MFMA16(aw, bh[tt], ya[ct][tt]);
            }
        }
    }
    __syncthreads();   // all fc2 reads of hs done before reuse as x2 staging

    // ---- stage 7: bias + LN2 + residual(x1s) -> x2s (overlays hs) ----
    {
        float4 pb4[2], wn4[2], bn4[2];
#pragma unroll
        for (int ct = 0; ct < 2; ++ct) {
            const int ob = wv*32 + ct*16 + quad*4;
            pb4[ct] = *(const float4*)&fc2bf[ob];
            wn4[ct] = *(const float4*)&n2wf[ob];
            bn4[ct] = *(const float4*)&n2bf[ob];
        }
#pragma unroll
        for (int tt = 0; tt < 4; ++tt) {
            float sv = 0.f;
#pragma unroll
            for (int ct = 0; ct < 2; ++ct)
#pragma unroll
                for (int r = 0; r < 4; ++r) {
                    ya[ct][tt][r] += ((const float*)&pb4[ct])[r];
                    sv += ya[ct][tt][r];
                }
            sv += __shfl_xor(sv, 16);
            sv += __shfl_xor(sv, 32);
            if (quad == 0) psum[wv*64 + tt*16 + l15] = sv;
        }
        __syncthreads();
        float mu[4];
#pragma unroll
        for (int tt = 0; tt < 4; ++tt) {
            const int tok = tt*16 + l15;
            mu[tt] = (psum[tok] + psum[64+tok] + psum[128+tok] + psum[192+tok]) * (1.0f/128.0f);
            float sv = 0.f;
#pragma unroll
            for (int ct = 0; ct < 2; ++ct)
#pragma unroll
                for (int r = 0; r < 4; ++r) {
                    const float d = ya[ct][tt][r] - mu[tt];
                    sv += d*d;
                }
            sv += __shfl_xor(sv, 16);
            sv += __shfl_xor(sv, 32);
            if (quad == 0) pvar[wv*64 + tok] = sv;
        }
        __syncthreads();
#pragma unroll
        for (int tt = 0; tt < 4; ++tt) {
            const int tok = tt*16 + l15;
            const float var = (pvar[tok] + pvar[64+tok] + pvar[128+tok] + pvar[192+tok]) * (1.0f/128.0f);
            const float rstd = rsqrtf(var + 1e-5f);
#pragma unroll
            for (int ct = 0; ct < 2; ++ct) {
                const int ob = wv*32 + ct*16 + quad*4;
                bf16x4 xr = *(const bf16x4*)(A + tok*256 + SWZ(tok, ob*2));
                float xv[4];
#pragma unroll
                for (int r = 0; r < 4; ++r)
                    xv[r] = bf2f(xr[r]) + (ya[ct][tt][r] - mu[tt]) * rstd * ((const float*)&wn4[ct])[r]
                            + ((const float*)&bn4[ct])[r];
                pack4(xv[0], xv[1], xv[2], xv[3], (bf16*)(Bv + tok*256 + SWZ(tok, ob*2)));
            }
        }
    }
    __syncthreads();

    // ---- stage 8: write x2 to planar (B, C, H, W) at reverse-shifted positions ----
    {
        const int wf0 = ww*8 + 4;
        const int wf1 = (ww*8 + 8) & 127;
#pragma unroll
        for (int g = 0; g < 4; ++g) {
            const int idx = g*256 + tid;          // 0..1023 = (rr, c)
            const int c  = idx & 127;
            const int rr = idx >> 7;
            const int hf = (wh*8 + rr + 4) & 127;
            const size_t rowb = ((size_t)(b*128 + c))*16384 + (size_t)hf*128;
            unsigned short xv[8];
#pragma unroll
            for (int k2 = 0; k2 < 8; ++k2) {
                const int tb = rr*8 + k2;
                xv[k2] = *(const unsigned short*)(Bv + tb*256 + SWZ(tb, c*2));
            }
            if (!isf) {
                uint2 u0, u1;
                u0.x = (unsigned)xv[0] | ((unsigned)xv[1] << 16);
                u0.y = (unsigned)xv[2] | ((unsigned)xv[3] << 16);
                u1.x = (unsigned)xv[4] | ((unsigned)xv[5] << 16);
                u1.y = (unsigned)xv[6] | ((unsigned)xv[7] << 16);
                bf16* dstb = (bf16*)out;
                *(uint2*)(dstb + rowb + wf0) = u0;
                *(uint2*)(dstb + rowb + wf1) = u1;
            } else {
                float4 u0, u1;
                const bf16* xb = (const bf16*)xv;
                u0.x = bf2f(xb[0]); u0.y = bf2f(xb[1]); u0.z = bf2f(xb[2]); u0.w = bf2f(xb[3]);
                u1.x = bf2f(xb[4]); u1.y = bf2f(xb[5]); u1.z = bf2f(xb[6]); u1.w = bf2f(xb[7]);
                float* dstf = (float*)out;
                *(float4*)(dstf + rowb + wf0) = u0;
                *(float4*)(dstf + rowb + wf1) = u1;
            }
        }
    }
}

extern "C" void kernel_launch(void* const* d_in, const int* in_sizes, int n_in,
                              void* d_out, int out_size, void* d_ws, size_t ws_size,
                              hipStream_t stream)
{
    (void)in_sizes; (void)n_in; (void)out_size; (void)ws_size;
    const void* x      = d_in[0];
    const void* n1w    = d_in[1];
    const void* n1b    = d_in[2];
    const void* qkv_w  = d_in[3];
    const void* q_bias = d_in[4];
    const void* v_bias = d_in[5];
    const void* lscale = d_in[6];
    const void* cpb_w1 = d_in[7];
    const void* cpb_b1 = d_in[8];
    const void* cpb_w2 = d_in[9];
    const void* proj_w = d_in[10];
    const void* proj_b = d_in[11];
    const void* n2w    = d_in[12];
    const void* n2b    = d_in[13];
    const void* fc1w   = d_in[14];
    const void* fc1b   = d_in[15];
    const void* fc2w   = d_in[16];
    const void* fc2b   = d_in[17];

    char*  ws      = (char*)d_ws;
    float* biasAll = (float*)ws;
    float* scales  = (float*)(ws + OFF_SCALES);
    int*   flag    = (int*)(ws + OFF_FLAG);

    k_init<<<dim3(97), dim3(256), 0, stream>>>(cpb_w1, cpb_b1, cpb_w2, lscale,
                                               qkv_w, proj_w, fc1w, fc2w,
                                               q_bias, v_bias, proj_b, n1w, n1b,
                                               fc1b, fc2b, n2w, n2b, ws);
    k_fused<<<dim3(4096), dim3(256), 0, stream>>>(x,
        (const bf16*)(ws + OFF_QKVW), (const float*)(ws + OFF_QKVB),
        (const bf16*)(ws + OFF_PROJW), (const float*)(ws + OFF_PROJB),
        (const float*)(ws + OFF_N1W), (const float*)(ws + OFF_N1B),
        (const bf16*)(ws + OFF_FC1W), (const float*)(ws + OFF_FC1B),
        (const bf16*)(ws + OFF_FC2W), (const float*)(ws + OFF_FC2B),
        (const float*)(ws + OFF_N2W), (const float*)(ws + OFF_N2B),
        biasAll, scales, flag, d_out);
}